// Round 1
// baseline (3037.392 us; speedup 1.0000x reference)
//
#include <hip/hip_runtime.h>
#include <hip/hip_bf16.h>
#include <cstdint>
#include <cstddef>

#define Bq 8192
#define Sq 21
#define Hq 1024
#define Mq (Bq * Sq)   // 172032

typedef __attribute__((ext_vector_type(8))) short short8;
typedef __attribute__((ext_vector_type(4))) float floatx4;

__device__ __forceinline__ short f2b(float x) {
    // RNE float -> bf16 bits (finite inputs only)
    unsigned u = __builtin_bit_cast(unsigned, x);
    unsigned r = (u + 0x7fffu + ((u >> 16) & 1u)) >> 16;
    return (short)r;
}
__device__ __forceinline__ float b2f(unsigned short b) {
    return __builtin_bit_cast(float, (unsigned)b << 16);
}

// fast tanh: 1 - 2/(e^{2x}+1).  v_exp + v_rcp, exact at +-inf, |err|~1e-6.
__device__ __forceinline__ float fast_tanh(float x) {
    float e = __expf(2.0f * x);
    return fmaf(-2.0f, __builtin_amdgcn_rcpf(e + 1.0f), 1.0f);
}

// async global->LDS, 16B per lane; LDS dest = wave-uniform base + lane*16
__device__ __forceinline__ void gl_lds16(const void* g, void* l) {
    __builtin_amdgcn_global_load_lds(
        (const __attribute__((address_space(1))) unsigned int*)g,
        (__attribute__((address_space(3))) unsigned int*)l, 16, 0, 0);
}

// ---------------------------------------------------------------------------
// transpose + convert [K][N] fp32 -> [N][K] bf16
// ---------------------------------------------------------------------------
__global__ void transpose_cvt(const float* __restrict__ src,
                              unsigned short* __restrict__ dst) {
    __shared__ float tile[32][33];
    const int n0 = blockIdx.x * 32;
    const int k0 = blockIdx.y * 32;
    const int tx = threadIdx.x;
    const int ty = threadIdx.y;
    #pragma unroll
    for (int i = ty; i < 32; i += 8)
        tile[i][tx] = src[(size_t)(k0 + i) * Hq + n0 + tx];
    __syncthreads();
    #pragma unroll
    for (int i = ty; i < 32; i += 8)
        dst[(size_t)(n0 + i) * Hq + k0 + tx] = (unsigned short)f2b(tile[tx][i]);
}

// ---------------------------------------------------------------------------
// fp32 -> bf16 bulk convert (n8 = elements/8)
// ---------------------------------------------------------------------------
__global__ __launch_bounds__(256) void cvt_bf16(const float* __restrict__ src,
                                                unsigned short* __restrict__ dst,
                                                int n8) {
    int i = blockIdx.x * 256 + threadIdx.x;
    const int stride = gridDim.x * 256;
    for (; i < n8; i += stride) {
        const float4* s4 = reinterpret_cast<const float4*>(src) + (size_t)i * 2;
        float4 a = s4[0], b = s4[1];
        short8 p;
        p[0] = f2b(a.x); p[1] = f2b(a.y); p[2] = f2b(a.z); p[3] = f2b(a.w);
        p[4] = f2b(b.x); p[5] = f2b(b.y); p[6] = f2b(b.z); p[7] = f2b(b.w);
        reinterpret_cast<short8*>(dst)[i] = p;
    }
}

// ---------------------------------------------------------------------------
// m97-style GEMM: 128x128 tile, BK=64, bf16 A/B, global_load_lds staging,
// XOR-swizzled unpadded LDS.  Kernel A: wc = c @ W (stores fp32 wc).
// (kept unchanged — small kernel, ~40-60us)
// ---------------------------------------------------------------------------
__global__ __launch_bounds__(256, 3) void gemm_wc2(
    const unsigned short* __restrict__ cb, const unsigned short* __restrict__ Wtr,
    float* __restrict__ wc)
{
    __shared__ unsigned short As[128 * 64];
    __shared__ unsigned short Bs[128 * 64];

    const int n0 = blockIdx.x * 128;
    const int m0 = blockIdx.y * 128;
    const int t = threadIdx.x;
    const int lane = t & 63;
    const int w = t >> 6;

    const int sub = lane >> 3;          // 0..7
    const int k8g = (lane & 7) ^ sub;   // swizzled source k-chunk
    const unsigned short* ap[4];
    const unsigned short* bp[4];
    #pragma unroll
    for (int j = 0; j < 4; ++j) {
        const int r = w * 32 + j * 8 + sub;
        ap[j] = cb + (size_t)(m0 + r) * Hq + k8g * 8;
        bp[j] = Wtr + (size_t)(n0 + r) * Hq + k8g * 8;
    }

    const int wm = (w & 1) * 64;
    const int wn = (w >> 1) * 64;
    const int l15 = lane & 15;
    const int q = lane >> 4;
    const int sw = l15 & 7;

    floatx4 acc[4][4] = {};
    const short8* AsV = (const short8*)As;
    const short8* BsV = (const short8*)Bs;

    for (int k0 = 0; k0 < Hq; k0 += 64) {
        __syncthreads();
        #pragma unroll
        for (int j = 0; j < 4; ++j) {
            gl_lds16(ap[j] + k0, &As[(w * 256 + j * 64) * 8]);
            gl_lds16(bp[j] + k0, &Bs[(w * 256 + j * 64) * 8]);
        }
        __syncthreads();
        #pragma unroll
        for (int kk = 0; kk < 2; ++kk) {
            const int k8 = kk * 4 + q;
            short8 af[4], bfr[4];
            #pragma unroll
            for (int i = 0; i < 4; ++i) {
                af[i]  = AsV[((wm + i * 16 + l15) << 3) | (k8 ^ sw)];
                bfr[i] = BsV[((wn + i * 16 + l15) << 3) | (k8 ^ sw)];
            }
            #pragma unroll
            for (int i = 0; i < 4; ++i)
                #pragma unroll
                for (int j = 0; j < 4; ++j)
                    acc[i][j] = __builtin_amdgcn_mfma_f32_16x16x32_bf16(
                        af[i], bfr[j], acc[i][j], 0, 0, 0);
        }
    }

    #pragma unroll
    for (int i = 0; i < 4; ++i)
        #pragma unroll
        for (int rr = 0; rr < 4; ++rr) {
            const int mm = m0 + wm + i * 16 + q * 4 + rr;
            #pragma unroll
            for (int j = 0; j < 4; ++j) {
                const int nn = n0 + wn + j * 16 + l15;
                wc[(size_t)mm * Hq + nn] = acc[i][j][rr];
            }
        }
}

// ---------------------------------------------------------------------------
// NEW Kernel B: 256x256-tile, 8-wave, double-buffered single-barrier pipeline.
// scores GEMM over rows m=(b,s) of bf16 allh; epilogue fast-tanh + Wt dot.
// LDS: 2 bufs x (A 256x64 + B 256x64) bf16 = 128 KiB, 1 block/CU.
// ---------------------------------------------------------------------------
__device__ __forceinline__ void stage_step(
    unsigned short* __restrict__ buf, int w,
    const unsigned short* const (&ap)[4], const unsigned short* const (&bp)[4],
    int k0)
{
    unsigned short* dstA = buf + w * 2048;            // w*32 rows * 64 cols
    unsigned short* dstB = buf + 16384 + w * 2048;
    #pragma unroll
    for (int j = 0; j < 4; ++j) {
        gl_lds16(ap[j] + k0, dstA + j * 512);         // 8 rows / wave-load
        gl_lds16(bp[j] + k0, dstB + j * 512);
    }
}

__device__ __forceinline__ void compute_step(
    const unsigned short* __restrict__ buf,
    floatx4 (&acc)[8][4], int wm, int wn, int l15, int q, int sw)
{
    const short8* AsV = (const short8*)buf;
    const short8* BsV = (const short8*)(buf + 16384);
    #pragma unroll
    for (int kk = 0; kk < 2; ++kk) {
        const int k8 = kk * 4 + q;
        short8 af[8], bfv[4];
        #pragma unroll
        for (int i = 0; i < 8; ++i)
            af[i] = AsV[((wm + i * 16 + l15) << 3) | (k8 ^ sw)];
        #pragma unroll
        for (int j = 0; j < 4; ++j)
            bfv[j] = BsV[((wn + j * 16 + l15) << 3) | (k8 ^ sw)];
        #pragma unroll
        for (int i = 0; i < 8; ++i)
            #pragma unroll
            for (int j = 0; j < 4; ++j)
                acc[i][j] = __builtin_amdgcn_mfma_f32_16x16x32_bf16(
                    af[i], bfv[j], acc[i][j], 0, 0, 0);
    }
}

__global__ __launch_bounds__(512, 2) void gemm_scores256(
    const unsigned short* __restrict__ hb, const unsigned short* __restrict__ Vt,
    const float* __restrict__ wc, const float* __restrict__ bias,
    const float* __restrict__ Wt, float* __restrict__ scores)
{
    __shared__ unsigned short lds[65536];   // [2 buf][A|B][256*64] = 128 KiB

    // XCD-chunked bijective swizzle: 2688 blocks, 2688 % 8 == 0.
    // XCD x owns contiguous m-panels; 4 n-blocks of a panel adjacent in time.
    const int orig = blockIdx.x;
    const int swz = (orig & 7) * 336 + (orig >> 3);
    const int n0 = (swz & 3) * 256;
    const int m0 = (swz >> 2) * 256;

    const int t = threadIdx.x;
    const int lane = t & 63;
    const int w = t >> 6;                 // 0..7

    const int sub = lane >> 3;            // row within 8-row group
    const int k8g = (lane & 7) ^ sub;     // pre-swizzled source k-chunk
    const unsigned short* ap[4];
    const unsigned short* bp[4];
    #pragma unroll
    for (int j = 0; j < 4; ++j) {
        const int r = w * 32 + j * 8 + sub;   // wave w stages rows w*32..w*32+31
        const int m = m0 + r;
        const int bb = m / 21;
        const int ss = m - bb * 21;
        ap[j] = hb + ((size_t)ss * Bq + bb) * Hq + k8g * 8;
        bp[j] = Vt + (size_t)(n0 + r) * Hq + k8g * 8;
    }

    // wave tile: 2(M) x 4(N) waves; per-wave output 128x64
    const int wm = (w >> 2) * 128;
    const int wn = (w & 3) * 64;
    const int l15 = lane & 15;
    const int q = lane >> 4;
    const int sw = l15 & 7;

    floatx4 acc[8][4] = {};

    unsigned short* buf0 = lds;
    unsigned short* buf1 = lds + 32768;

    // prologue: fill buf0 with K-tile 0
    stage_step(buf0, w, ap, bp, 0);
    __syncthreads();

    // steady state: one barrier per K-step; STAGE(next) issued before compute
    // so the 8 global_load_lds fly under 64 MFMA/wave, drained at the barrier.
    #pragma unroll 1
    for (int tt = 0; tt < 8; ++tt) {
        stage_step(buf1, w, ap, bp, tt * 128 + 64);
        compute_step(buf0, acc, wm, wn, l15, q, sw);
        __syncthreads();
        if (tt < 7) {
            stage_step(buf0, w, ap, bp, tt * 128 + 128);
            compute_step(buf1, acc, wm, wn, l15, q, sw);
            __syncthreads();
        } else {
            compute_step(buf1, acc, wm, wn, l15, q, sw);  // last tile, no stage
        }
    }

    // epilogue: e = tanh(acc + wc[b] + bias[s]); scores += e . Wt
    float wtv[4];
    #pragma unroll
    for (int j = 0; j < 4; ++j) wtv[j] = Wt[n0 + wn + j * 16 + l15];

    #pragma unroll
    for (int i = 0; i < 8; ++i) {
        #pragma unroll
        for (int rr = 0; rr < 4; ++rr) {
            const int mm = m0 + wm + i * 16 + q * 4 + rr;
            const int b2 = mm / 21;
            const int s2 = mm - b2 * 21;
            const float* wcrow = wc + (size_t)b2 * Hq + n0 + wn;
            const float* birow = bias + (size_t)s2 * Hq + n0 + wn;
            float part = 0.f;
            #pragma unroll
            for (int j = 0; j < 4; ++j) {
                const int nl = j * 16 + l15;
                float e = fast_tanh(acc[i][j][rr] + wcrow[nl] + birow[nl]);
                part += e * wtv[j];
            }
            part += __shfl_xor(part, 1);
            part += __shfl_xor(part, 2);
            part += __shfl_xor(part, 4);
            part += __shfl_xor(part, 8);
            if (l15 == 0) atomicAdd(&scores[mm], part);
        }
    }
}

// ---------------------------------------------------------------------------
// softmax over S=21 + y[b,:] = sum_s alpha_s h[s,b,:]  (bf16 h)
// ---------------------------------------------------------------------------
__global__ __launch_bounds__(256) void softmax_out2(
    const float* __restrict__ scores, const unsigned short* __restrict__ hb,
    float* __restrict__ out)
{
    const int b = blockIdx.x;
    const int t = threadIdx.x;

    float sc[Sq];
    float mx = -1e30f;
    #pragma unroll
    for (int s = 0; s < Sq; ++s) {
        sc[s] = scores[(size_t)b * Sq + s];
        mx = fmaxf(mx, sc[s]);
    }
    float sum = 0.f;
    #pragma unroll
    for (int s = 0; s < Sq; ++s) {
        sc[s] = __expf(sc[s] - mx);
        sum += sc[s];
    }
    const float inv = 1.0f / sum;

    const int h = t * 4;
    float a0 = 0.f, a1 = 0.f, a2 = 0.f, a3 = 0.f;
    #pragma unroll
    for (int s = 0; s < Sq; ++s) {
        const unsigned short* p = hb + ((size_t)s * Bq + b) * Hq + h;
        uint2 u = *reinterpret_cast<const uint2*>(p);
        a0 += sc[s] * b2f((unsigned short)(u.x & 0xffffu));
        a1 += sc[s] * b2f((unsigned short)(u.x >> 16));
        a2 += sc[s] * b2f((unsigned short)(u.y & 0xffffu));
        a3 += sc[s] * b2f((unsigned short)(u.y >> 16));
    }
    float4 r;
    r.x = a0 * inv; r.y = a1 * inv; r.z = a2 * inv; r.w = a3 * inv;
    *reinterpret_cast<float4*>(out + (size_t)b * Hq + h) = r;
}

// ===========================================================================
// Fallback path (round-1, needs only ~38 MB ws) — used if ws_size too small.
// ===========================================================================
__global__ __launch_bounds__(256, 2) void gemm_wc_fb(
    const float* __restrict__ c, const unsigned short* __restrict__ Wtr,
    float* __restrict__ wc)
{
    __shared__ short As[128][72];
    __shared__ short Bs[128][72];
    const int m0 = blockIdx.x * 128;
    const int n0 = blockIdx.y * 128;
    const int t = threadIdx.x;
    const int r = t >> 1;
    const int half = t & 1;
    const float*          arow = c + (size_t)(m0 + r) * Hq + half * 32;
    const unsigned short* brow = Wtr + (size_t)(n0 + r) * Hq + half * 32;
    const int lane = t & 63;
    const int w = t >> 6;
    const int wm = (w & 1) * 64;
    const int wn = (w >> 1) * 64;
    const int l15 = lane & 15;
    const int q = lane >> 4;
    floatx4 acc[4][4] = {};
    for (int k0 = 0; k0 < Hq; k0 += 64) {
        __syncthreads();
        const float4* a4 = reinterpret_cast<const float4*>(arow + k0);
        #pragma unroll
        for (int i = 0; i < 4; ++i) {
            float4 v0 = a4[2 * i], v1 = a4[2 * i + 1];
            short8 p;
            p[0] = f2b(v0.x); p[1] = f2b(v0.y); p[2] = f2b(v0.z); p[3] = f2b(v0.w);
            p[4] = f2b(v1.x); p[5] = f2b(v1.y); p[6] = f2b(v1.z); p[7] = f2b(v1.w);
            *reinterpret_cast<short8*>(&As[r][half * 32 + i * 8]) = p;
        }
        const short8* b8 = reinterpret_cast<const short8*>(brow + k0);
        #pragma unroll
        for (int i = 0; i < 4; ++i)
            *reinterpret_cast<short8*>(&Bs[r][half * 32 + i * 8]) = b8[i];
        __syncthreads();
        #pragma unroll
        for (int kk = 0; kk < 64; kk += 32) {
            short8 af[4], bfr[4];
            #pragma unroll
            for (int i = 0; i < 4; ++i)
                af[i] = *reinterpret_cast<const short8*>(&As[wm + i * 16 + l15][kk + q * 8]);
            #pragma unroll
            for (int j = 0; j < 4; ++j)
                bfr[j] = *reinterpret_cast<const short8*>(&Bs[wn + j * 16 + l15][kk + q * 8]);
            #pragma unroll
            for (int i = 0; i < 4; ++i)
                #pragma unroll
                for (int j = 0; j < 4; ++j)
                    acc[i][j] = __builtin_amdgcn_mfma_f32_16x16x32_bf16(
                        af[i], bfr[j], acc[i][j], 0, 0, 0);
        }
    }
    #pragma unroll
    for (int i = 0; i < 4; ++i)
        #pragma unroll
        for (int rr = 0; rr < 4; ++rr) {
            const int mm = m0 + wm + i * 16 + q * 4 + rr;
            #pragma unroll
            for (int j = 0; j < 4; ++j)
                wc[(size_t)mm * Hq + n0 + wn + j * 16 + l15] = acc[i][j][rr];
        }
}

__global__ __launch_bounds__(256, 2) void gemm_scores_fb(
    const float* __restrict__ allh, const unsigned short* __restrict__ Vt,
    const float* __restrict__ wc, const float* __restrict__ bias,
    const float* __restrict__ Wt, float* __restrict__ scores)
{
    __shared__ short As[128][72];
    __shared__ short Bs[128][72];
    const int m0 = blockIdx.x * 128;
    const int n0 = blockIdx.y * 128;
    const int t = threadIdx.x;
    const int r = t >> 1;
    const int half = t & 1;
    const int m = m0 + r;
    const int bb = m / 21;
    const int ss = m - bb * 21;
    const float* arow = allh + (size_t)ss * (Bq * Hq) + (size_t)bb * Hq + half * 32;
    const unsigned short* brow = Vt + (size_t)(n0 + r) * Hq + half * 32;
    const int lane = t & 63;
    const int w = t >> 6;
    const int wm = (w & 1) * 64;
    const int wn = (w >> 1) * 64;
    const int l15 = lane & 15;
    const int q = lane >> 4;
    floatx4 acc[4][4] = {};
    for (int k0 = 0; k0 < Hq; k0 += 64) {
        __syncthreads();
        const float4* a4 = reinterpret_cast<const float4*>(arow + k0);
        #pragma unroll
        for (int i = 0; i < 4; ++i) {
            float4 v0 = a4[2 * i], v1 = a4[2 * i + 1];
            short8 p;
            p[0] = f2b(v0.x); p[1] = f2b(v0.y); p[2] = f2b(v0.z); p[3] = f2b(v0.w);
            p[4] = f2b(v1.x); p[5] = f2b(v1.y); p[6] = f2b(v1.z); p[7] = f2b(v1.w);
            *reinterpret_cast<short8*>(&As[r][half * 32 + i * 8]) = p;
        }
        const short8* b8 = reinterpret_cast<const short8*>(brow + k0);
        #pragma unroll
        for (int i = 0; i < 4; ++i)
            *reinterpret_cast<short8*>(&Bs[r][half * 32 + i * 8]) = b8[i];
        __syncthreads();
        #pragma unroll
        for (int kk = 0; kk < 64; kk += 32) {
            short8 af[4], bfr[4];
            #pragma unroll
            for (int i = 0; i < 4; ++i)
                af[i] = *reinterpret_cast<const short8*>(&As[wm + i * 16 + l15][kk + q * 8]);
            #pragma unroll
            for (int j = 0; j < 4; ++j)
                bfr[j] = *reinterpret_cast<const short8*>(&Bs[wn + j * 16 + l15][kk + q * 8]);
            #pragma unroll
            for (int i = 0; i < 4; ++i)
                #pragma unroll
                for (int j = 0; j < 4; ++j)
                    acc[i][j] = __builtin_amdgcn_mfma_f32_16x16x32_bf16(
                        af[i], bfr[j], acc[i][j], 0, 0, 0);
        }
    }
    float wtv[4];
    #pragma unroll
    for (int j = 0; j < 4; ++j) wtv[j] = Wt[n0 + wn + j * 16 + l15];
    #pragma unroll
    for (int i = 0; i < 4; ++i)
        #pragma unroll
        for (int rr = 0; rr < 4; ++rr) {
            const int mm = m0 + wm + i * 16 + q * 4 + rr;
            const int b2 = mm / 21;
            const int s2 = mm - b2 * 21;
            const float* wcrow = wc + (size_t)b2 * Hq + n0 + wn;
            const float* birow = bias + (size_t)s2 * Hq + n0 + wn;
            float part = 0.f;
            #pragma unroll
            for (int j = 0; j < 4; ++j) {
                const int nl = j * 16 + l15;
                float e = tanhf(acc[i][j][rr] + wcrow[nl] + birow[nl]);
                part += e * wtv[j];
            }
            part += __shfl_xor(part, 1);
            part += __shfl_xor(part, 2);
            part += __shfl_xor(part, 4);
            part += __shfl_xor(part, 8);
            if (l15 == 0) atomicAdd(&scores[mm], part);
        }
}

__global__ __launch_bounds__(256) void softmax_out_fb(
    const float* __restrict__ scores, const float* __restrict__ allh,
    float* __restrict__ out)
{
    const int b = blockIdx.x;
    const int t = threadIdx.x;
    float sc[Sq];
    float mx = -1e30f;
    #pragma unroll
    for (int s = 0; s < Sq; ++s) {
        sc[s] = scores[(size_t)b * Sq + s];
        mx = fmaxf(mx, sc[s]);
    }
    float sum = 0.f;
    #pragma unroll
    for (int s = 0; s < Sq; ++s) {
        sc[s] = __expf(sc[s] - mx);
        sum += sc[s];
    }
    const float inv = 1.0f / sum;
    for (int h = t; h < Hq; h += 256) {
        float acc = 0.f;
        #pragma unroll
        for (int s = 0; s < Sq; ++s)
            acc += sc[s] * allh[(size_t)s * (Bq * Hq) + (size_t)b * Hq + h];
        out[(size_t)b * Hq + h] = acc * inv;
    }
}

// ---------------------------------------------------------------------------
extern "C" void kernel_launch(void* const* d_in, const int* in_sizes, int n_in,
                              void* d_out, int out_size, void* d_ws, size_t ws_size,
                              hipStream_t stream) {
    const float* c    = (const float*)d_in[0];
    const float* allh = (const float*)d_in[1];
    const float* W    = (const float*)d_in[2];
    const float* V    = (const float*)d_in[3];
    const float* bias = (const float*)d_in[4];
    const float* Wt   = (const float*)d_in[5];
    float* out = (float*)d_out;
    char* ws = (char*)d_ws;

    const size_t NEED = 411041792ULL;  // ~392 MiB fast-path scratch

    if (ws_size >= NEED) {
        unsigned short* Vt  = (unsigned short*)ws;                 // 2 MB
        unsigned short* Wtr = (unsigned short*)(ws + 2097152);     // 2 MB
        float* wc           = (float*)(ws + 4194304);              // 32 MB
        float* scores       = (float*)(ws + 37748736);             // 688 KB
        unsigned short* cb  = (unsigned short*)(ws + 41943040);    // 16 MB
        unsigned short* hb  = (unsigned short*)(ws + 58720256);    // 336 MB

        hipMemsetAsync(scores, 0, (size_t)Bq * Sq * sizeof(float), stream);
        transpose_cvt<<<dim3(32, 32), dim3(32, 8), 0, stream>>>(W, Wtr);
        transpose_cvt<<<dim3(32, 32), dim3(32, 8), 0, stream>>>(V, Vt);
        cvt_bf16<<<1024, 256, 0, stream>>>(c, cb, Bq * Hq / 8);
        cvt_bf16<<<4096, 256, 0, stream>>>(allh, hb, Sq * (Bq / 8) * Hq);

        gemm_wc2<<<dim3(Hq / 128, Bq / 128), 256, 0, stream>>>(cb, Wtr, wc);
        gemm_scores256<<<dim3((Mq / 256) * (Hq / 256)), dim3(512), 0, stream>>>(
            hb, Vt, wc, bias, Wt, scores);
        softmax_out2<<<Bq, 256, 0, stream>>>(scores, hb, out);
    } else {
        unsigned short* Vt  = (unsigned short*)ws;
        unsigned short* Wtr = (unsigned short*)(ws + (2u << 20));
        float* wc     = (float*)(ws + (4u << 20));
        float* scores = (float*)(ws + (4u << 20) + (size_t)Bq * Hq * 4);

        hipMemsetAsync(scores, 0, (size_t)Bq * Sq * sizeof(float), stream);
        transpose_cvt<<<dim3(32, 32), dim3(32, 8), 0, stream>>>(W, Wtr);
        transpose_cvt<<<dim3(32, 32), dim3(32, 8), 0, stream>>>(V, Vt);
        gemm_wc_fb<<<dim3(Bq / 128, Hq / 128), 256, 0, stream>>>(c, Wtr, wc);
        gemm_scores_fb<<<dim3(Mq / 128, Hq / 128), 256, 0, stream>>>(
            allh, Vt, wc, bias, Wt, scores);
        softmax_out_fb<<<Bq, 256, 0, stream>>>(scores, allh, out);
    }
}

// Round 2
// 3033.737 us; speedup vs baseline: 1.0012x; 1.0012x over previous
//
#include <hip/hip_runtime.h>
#include <hip/hip_bf16.h>
#include <cstdint>
#include <cstddef>

#define Bq 8192
#define Sq 21
#define Hq 1024
#define Mq (Bq * Sq)   // 172032

typedef __attribute__((ext_vector_type(8))) short short8;
typedef __attribute__((ext_vector_type(4))) float floatx4;

__device__ __forceinline__ short f2b(float x) {
    // RNE float -> bf16 bits (finite inputs only)
    unsigned u = __builtin_bit_cast(unsigned, x);
    unsigned r = (u + 0x7fffu + ((u >> 16) & 1u)) >> 16;
    return (short)r;
}
__device__ __forceinline__ float b2f(unsigned short b) {
    return __builtin_bit_cast(float, (unsigned)b << 16);
}

// fast tanh: 1 - 2/(e^{2x}+1).  v_exp + v_rcp, exact at +-inf, |err|~1e-6.
__device__ __forceinline__ float fast_tanh(float x) {
    float e = __expf(2.0f * x);
    return fmaf(-2.0f, __builtin_amdgcn_rcpf(e + 1.0f), 1.0f);
}

// async global->LDS, 16B per lane; LDS dest = wave-uniform base + lane*16
__device__ __forceinline__ void gl_lds16(const void* g, void* l) {
    __builtin_amdgcn_global_load_lds(
        (const __attribute__((address_space(1))) unsigned int*)g,
        (__attribute__((address_space(3))) unsigned int*)l, 16, 0, 0);
}

// ---------------------------------------------------------------------------
// transpose + convert [K][N] fp32 -> [N][K] bf16
// ---------------------------------------------------------------------------
__global__ void transpose_cvt(const float* __restrict__ src,
                              unsigned short* __restrict__ dst) {
    __shared__ float tile[32][33];
    const int n0 = blockIdx.x * 32;
    const int k0 = blockIdx.y * 32;
    const int tx = threadIdx.x;
    const int ty = threadIdx.y;
    #pragma unroll
    for (int i = ty; i < 32; i += 8)
        tile[i][tx] = src[(size_t)(k0 + i) * Hq + n0 + tx];
    __syncthreads();
    #pragma unroll
    for (int i = ty; i < 32; i += 8)
        dst[(size_t)(n0 + i) * Hq + k0 + tx] = (unsigned short)f2b(tile[tx][i]);
}

// ---------------------------------------------------------------------------
// fp32 -> bf16 bulk convert (n8 = elements/8)
// ---------------------------------------------------------------------------
__global__ __launch_bounds__(256) void cvt_bf16(const float* __restrict__ src,
                                                unsigned short* __restrict__ dst,
                                                int n8) {
    int i = blockIdx.x * 256 + threadIdx.x;
    const int stride = gridDim.x * 256;
    for (; i < n8; i += stride) {
        const float4* s4 = reinterpret_cast<const float4*>(src) + (size_t)i * 2;
        float4 a = s4[0], b = s4[1];
        short8 p;
        p[0] = f2b(a.x); p[1] = f2b(a.y); p[2] = f2b(a.z); p[3] = f2b(a.w);
        p[4] = f2b(b.x); p[5] = f2b(b.y); p[6] = f2b(b.z); p[7] = f2b(b.w);
        reinterpret_cast<short8*>(dst)[i] = p;
    }
}

// ---------------------------------------------------------------------------
// m97-style GEMM: 128x128 tile, BK=64, bf16 A/B, global_load_lds staging,
// XOR-swizzled unpadded LDS.  Kernel A: wc = c @ W (stores fp32 wc).
// ---------------------------------------------------------------------------
__global__ __launch_bounds__(256, 3) void gemm_wc2(
    const unsigned short* __restrict__ cb, const unsigned short* __restrict__ Wtr,
    float* __restrict__ wc)
{
    __shared__ unsigned short As[128 * 64];
    __shared__ unsigned short Bs[128 * 64];

    const int n0 = blockIdx.x * 128;
    const int m0 = blockIdx.y * 128;
    const int t = threadIdx.x;
    const int lane = t & 63;
    const int w = t >> 6;

    const int sub = lane >> 3;          // 0..7
    const int k8g = (lane & 7) ^ sub;   // swizzled source k-chunk
    const unsigned short* ap[4];
    const unsigned short* bp[4];
    #pragma unroll
    for (int j = 0; j < 4; ++j) {
        const int r = w * 32 + j * 8 + sub;
        ap[j] = cb + (size_t)(m0 + r) * Hq + k8g * 8;
        bp[j] = Wtr + (size_t)(n0 + r) * Hq + k8g * 8;
    }

    const int wm = (w & 1) * 64;
    const int wn = (w >> 1) * 64;
    const int l15 = lane & 15;
    const int q = lane >> 4;
    const int sw = l15 & 7;

    floatx4 acc[4][4] = {};
    const short8* AsV = (const short8*)As;
    const short8* BsV = (const short8*)Bs;

    for (int k0 = 0; k0 < Hq; k0 += 64) {
        __syncthreads();
        #pragma unroll
        for (int j = 0; j < 4; ++j) {
            gl_lds16(ap[j] + k0, &As[(w * 256 + j * 64) * 8]);
            gl_lds16(bp[j] + k0, &Bs[(w * 256 + j * 64) * 8]);
        }
        __syncthreads();
        #pragma unroll
        for (int kk = 0; kk < 2; ++kk) {
            const int k8 = kk * 4 + q;
            short8 af[4], bfr[4];
            #pragma unroll
            for (int i = 0; i < 4; ++i) {
                af[i]  = AsV[((wm + i * 16 + l15) << 3) | (k8 ^ sw)];
                bfr[i] = BsV[((wn + i * 16 + l15) << 3) | (k8 ^ sw)];
            }
            #pragma unroll
            for (int i = 0; i < 4; ++i)
                #pragma unroll
                for (int j = 0; j < 4; ++j)
                    acc[i][j] = __builtin_amdgcn_mfma_f32_16x16x32_bf16(
                        af[i], bfr[j], acc[i][j], 0, 0, 0);
        }
    }

    #pragma unroll
    for (int i = 0; i < 4; ++i)
        #pragma unroll
        for (int rr = 0; rr < 4; ++rr) {
            const int mm = m0 + wm + i * 16 + q * 4 + rr;
            #pragma unroll
            for (int j = 0; j < 4; ++j) {
                const int nn = n0 + wn + j * 16 + l15;
                wc[(size_t)mm * Hq + nn] = acc[i][j][rr];
            }
        }
}

// ---------------------------------------------------------------------------
// Kernel B: 256x256-tile, 8-wave, double-buffered single-barrier pipeline.
// scores GEMM over rows m=(b,s) of bf16 allh; epilogue fast-tanh + Wt dot.
// LDS: 2 bufs x (A 256x64 + B 256x64) bf16 = 128 KiB, 1 block/CU.
// __launch_bounds__(512, 1): 2 waves/SIMD -> 256-VGPR budget.  The round-1
// (512,2) variant capped VGPRs at 128 and spilled the 128-VGPR accumulator
// to scratch (WRITE_SIZE 3.38 GB).  acc(128)+frags(48)+addr(~40) needs ~220.
// ---------------------------------------------------------------------------
__device__ __forceinline__ void stage_step(
    unsigned short* __restrict__ buf, int w,
    const unsigned short* const (&ap)[4], const unsigned short* const (&bp)[4],
    int k0)
{
    unsigned short* dstA = buf + w * 2048;            // w*32 rows * 64 cols
    unsigned short* dstB = buf + 16384 + w * 2048;
    #pragma unroll
    for (int j = 0; j < 4; ++j) {
        gl_lds16(ap[j] + k0, dstA + j * 512);         // 8 rows / wave-load
        gl_lds16(bp[j] + k0, dstB + j * 512);
    }
}

__device__ __forceinline__ void compute_step(
    const unsigned short* __restrict__ buf,
    floatx4 (&acc)[8][4], int wm, int wn, int l15, int q, int sw)
{
    const short8* AsV = (const short8*)buf;
    const short8* BsV = (const short8*)(buf + 16384);
    #pragma unroll
    for (int kk = 0; kk < 2; ++kk) {
        const int k8 = kk * 4 + q;
        short8 af[8], bfv[4];
        #pragma unroll
        for (int i = 0; i < 8; ++i)
            af[i] = AsV[((wm + i * 16 + l15) << 3) | (k8 ^ sw)];
        #pragma unroll
        for (int j = 0; j < 4; ++j)
            bfv[j] = BsV[((wn + j * 16 + l15) << 3) | (k8 ^ sw)];
        #pragma unroll
        for (int i = 0; i < 8; ++i)
            #pragma unroll
            for (int j = 0; j < 4; ++j)
                acc[i][j] = __builtin_amdgcn_mfma_f32_16x16x32_bf16(
                    af[i], bfv[j], acc[i][j], 0, 0, 0);
    }
}

__global__ __launch_bounds__(512, 1) void gemm_scores256(
    const unsigned short* __restrict__ hb, const unsigned short* __restrict__ Vt,
    const float* __restrict__ wc, const float* __restrict__ bias,
    const float* __restrict__ Wt, float* __restrict__ scores)
{
    __shared__ unsigned short lds[65536];   // [2 buf][A|B][256*64] = 128 KiB

    // XCD-chunked bijective swizzle: 2688 blocks, 2688 % 8 == 0.
    // XCD x owns contiguous m-panels; 4 n-blocks of a panel adjacent in time.
    const int orig = blockIdx.x;
    const int swz = (orig & 7) * 336 + (orig >> 3);
    const int n0 = (swz & 3) * 256;
    const int m0 = (swz >> 2) * 256;

    const int t = threadIdx.x;
    const int lane = t & 63;
    const int w = t >> 6;                 // 0..7

    const int sub = lane >> 3;            // row within 8-row group
    const int k8g = (lane & 7) ^ sub;     // pre-swizzled source k-chunk
    const unsigned short* ap[4];
    const unsigned short* bp[4];
    #pragma unroll
    for (int j = 0; j < 4; ++j) {
        const int r = w * 32 + j * 8 + sub;   // wave w stages rows w*32..w*32+31
        const int m = m0 + r;
        const int bb = m / 21;
        const int ss = m - bb * 21;
        ap[j] = hb + ((size_t)ss * Bq + bb) * Hq + k8g * 8;
        bp[j] = Vt + (size_t)(n0 + r) * Hq + k8g * 8;
    }

    // wave tile: 2(M) x 4(N) waves; per-wave output 128x64
    const int wm = (w >> 2) * 128;
    const int wn = (w & 3) * 64;
    const int l15 = lane & 15;
    const int q = lane >> 4;
    const int sw = l15 & 7;

    floatx4 acc[8][4] = {};

    unsigned short* buf0 = lds;
    unsigned short* buf1 = lds + 32768;

    // prologue: fill buf0 with K-tile 0
    stage_step(buf0, w, ap, bp, 0);
    __syncthreads();

    // steady state: one barrier per K-step; STAGE(next) issued before compute
    // so the 8 global_load_lds fly under 64 MFMA/wave, drained at the barrier.
    #pragma unroll 1
    for (int tt = 0; tt < 8; ++tt) {
        stage_step(buf1, w, ap, bp, tt * 128 + 64);
        compute_step(buf0, acc, wm, wn, l15, q, sw);
        __syncthreads();
        if (tt < 7) {
            stage_step(buf0, w, ap, bp, tt * 128 + 128);
            compute_step(buf1, acc, wm, wn, l15, q, sw);
            __syncthreads();
        } else {
            compute_step(buf1, acc, wm, wn, l15, q, sw);  // last tile, no stage
        }
    }

    // epilogue: e = tanh(acc + wc[b] + bias[s]); scores += e . Wt
    float wtv[4];
    #pragma unroll
    for (int j = 0; j < 4; ++j) wtv[j] = Wt[n0 + wn + j * 16 + l15];

    #pragma unroll
    for (int i = 0; i < 8; ++i) {
        #pragma unroll
        for (int rr = 0; rr < 4; ++rr) {
            const int mm = m0 + wm + i * 16 + q * 4 + rr;
            const int b2 = mm / 21;
            const int s2 = mm - b2 * 21;
            const float* wcrow = wc + (size_t)b2 * Hq + n0 + wn;
            const float* birow = bias + (size_t)s2 * Hq + n0 + wn;
            float part = 0.f;
            #pragma unroll
            for (int j = 0; j < 4; ++j) {
                const int nl = j * 16 + l15;
                float e = fast_tanh(acc[i][j][rr] + wcrow[nl] + birow[nl]);
                part += e * wtv[j];
            }
            part += __shfl_xor(part, 1);
            part += __shfl_xor(part, 2);
            part += __shfl_xor(part, 4);
            part += __shfl_xor(part, 8);
            if (l15 == 0) atomicAdd(&scores[mm], part);
        }
    }
}

// ---------------------------------------------------------------------------
// softmax over S=21 + y[b,:] = sum_s alpha_s h[s,b,:]  (bf16 h)
// ---------------------------------------------------------------------------
__global__ __launch_bounds__(256) void softmax_out2(
    const float* __restrict__ scores, const unsigned short* __restrict__ hb,
    float* __restrict__ out)
{
    const int b = blockIdx.x;
    const int t = threadIdx.x;

    float sc[Sq];
    float mx = -1e30f;
    #pragma unroll
    for (int s = 0; s < Sq; ++s) {
        sc[s] = scores[(size_t)b * Sq + s];
        mx = fmaxf(mx, sc[s]);
    }
    float sum = 0.f;
    #pragma unroll
    for (int s = 0; s < Sq; ++s) {
        sc[s] = __expf(sc[s] - mx);
        sum += sc[s];
    }
    const float inv = 1.0f / sum;

    const int h = t * 4;
    float a0 = 0.f, a1 = 0.f, a2 = 0.f, a3 = 0.f;
    #pragma unroll
    for (int s = 0; s < Sq; ++s) {
        const unsigned short* p = hb + ((size_t)s * Bq + b) * Hq + h;
        uint2 u = *reinterpret_cast<const uint2*>(p);
        a0 += sc[s] * b2f((unsigned short)(u.x & 0xffffu));
        a1 += sc[s] * b2f((unsigned short)(u.x >> 16));
        a2 += sc[s] * b2f((unsigned short)(u.y & 0xffffu));
        a3 += sc[s] * b2f((unsigned short)(u.y >> 16));
    }
    float4 r;
    r.x = a0 * inv; r.y = a1 * inv; r.z = a2 * inv; r.w = a3 * inv;
    *reinterpret_cast<float4*>(out + (size_t)b * Hq + h) = r;
}

// ===========================================================================
// Fallback path (round-1, needs only ~38 MB ws) — used if ws_size too small.
// ===========================================================================
__global__ __launch_bounds__(256, 2) void gemm_wc_fb(
    const float* __restrict__ c, const unsigned short* __restrict__ Wtr,
    float* __restrict__ wc)
{
    __shared__ short As[128][72];
    __shared__ short Bs[128][72];
    const int m0 = blockIdx.x * 128;
    const int n0 = blockIdx.y * 128;
    const int t = threadIdx.x;
    const int r = t >> 1;
    const int half = t & 1;
    const float*          arow = c + (size_t)(m0 + r) * Hq + half * 32;
    const unsigned short* brow = Wtr + (size_t)(n0 + r) * Hq + half * 32;
    const int lane = t & 63;
    const int w = t >> 6;
    const int wm = (w & 1) * 64;
    const int wn = (w >> 1) * 64;
    const int l15 = lane & 15;
    const int q = lane >> 4;
    floatx4 acc[4][4] = {};
    for (int k0 = 0; k0 < Hq; k0 += 64) {
        __syncthreads();
        const float4* a4 = reinterpret_cast<const float4*>(arow + k0);
        #pragma unroll
        for (int i = 0; i < 4; ++i) {
            float4 v0 = a4[2 * i], v1 = a4[2 * i + 1];
            short8 p;
            p[0] = f2b(v0.x); p[1] = f2b(v0.y); p[2] = f2b(v0.z); p[3] = f2b(v0.w);
            p[4] = f2b(v1.x); p[5] = f2b(v1.y); p[6] = f2b(v1.z); p[7] = f2b(v1.w);
            *reinterpret_cast<short8*>(&As[r][half * 32 + i * 8]) = p;
        }
        const short8* b8 = reinterpret_cast<const short8*>(brow + k0);
        #pragma unroll
        for (int i = 0; i < 4; ++i)
            *reinterpret_cast<short8*>(&Bs[r][half * 32 + i * 8]) = b8[i];
        __syncthreads();
        #pragma unroll
        for (int kk = 0; kk < 64; kk += 32) {
            short8 af[4], bfr[4];
            #pragma unroll
            for (int i = 0; i < 4; ++i)
                af[i] = *reinterpret_cast<const short8*>(&As[wm + i * 16 + l15][kk + q * 8]);
            #pragma unroll
            for (int j = 0; j < 4; ++j)
                bfr[j] = *reinterpret_cast<const short8*>(&Bs[wn + j * 16 + l15][kk + q * 8]);
            #pragma unroll
            for (int i = 0; i < 4; ++i)
                #pragma unroll
                for (int j = 0; j < 4; ++j)
                    acc[i][j] = __builtin_amdgcn_mfma_f32_16x16x32_bf16(
                        af[i], bfr[j], acc[i][j], 0, 0, 0);
        }
    }
    #pragma unroll
    for (int i = 0; i < 4; ++i)
        #pragma unroll
        for (int rr = 0; rr < 4; ++rr) {
            const int mm = m0 + wm + i * 16 + q * 4 + rr;
            #pragma unroll
            for (int j = 0; j < 4; ++j)
                wc[(size_t)mm * Hq + n0 + wn + j * 16 + l15] = acc[i][j][rr];
        }
}

__global__ __launch_bounds__(256, 2) void gemm_scores_fb(
    const float* __restrict__ allh, const unsigned short* __restrict__ Vt,
    const float* __restrict__ wc, const float* __restrict__ bias,
    const float* __restrict__ Wt, float* __restrict__ scores)
{
    __shared__ short As[128][72];
    __shared__ short Bs[128][72];
    const int m0 = blockIdx.x * 128;
    const int n0 = blockIdx.y * 128;
    const int t = threadIdx.x;
    const int r = t >> 1;
    const int half = t & 1;
    const int m = m0 + r;
    const int bb = m / 21;
    const int ss = m - bb * 21;
    const float* arow = allh + (size_t)ss * (Bq * Hq) + (size_t)bb * Hq + half * 32;
    const unsigned short* brow = Vt + (size_t)(n0 + r) * Hq + half * 32;
    const int lane = t & 63;
    const int w = t >> 6;
    const int wm = (w & 1) * 64;
    const int wn = (w >> 1) * 64;
    const int l15 = lane & 15;
    const int q = lane >> 4;
    floatx4 acc[4][4] = {};
    for (int k0 = 0; k0 < Hq; k0 += 64) {
        __syncthreads();
        const float4* a4 = reinterpret_cast<const float4*>(arow + k0);
        #pragma unroll
        for (int i = 0; i < 4; ++i) {
            float4 v0 = a4[2 * i], v1 = a4[2 * i + 1];
            short8 p;
            p[0] = f2b(v0.x); p[1] = f2b(v0.y); p[2] = f2b(v0.z); p[3] = f2b(v0.w);
            p[4] = f2b(v1.x); p[5] = f2b(v1.y); p[6] = f2b(v1.z); p[7] = f2b(v1.w);
            *reinterpret_cast<short8*>(&As[r][half * 32 + i * 8]) = p;
        }
        const short8* b8 = reinterpret_cast<const short8*>(brow + k0);
        #pragma unroll
        for (int i = 0; i < 4; ++i)
            *reinterpret_cast<short8*>(&Bs[r][half * 32 + i * 8]) = b8[i];
        __syncthreads();
        #pragma unroll
        for (int kk = 0; kk < 64; kk += 32) {
            short8 af[4], bfr[4];
            #pragma unroll
            for (int i = 0; i < 4; ++i)
                af[i] = *reinterpret_cast<const short8*>(&As[wm + i * 16 + l15][kk + q * 8]);
            #pragma unroll
            for (int j = 0; j < 4; ++j)
                bfr[j] = *reinterpret_cast<const short8*>(&Bs[wn + j * 16 + l15][kk + q * 8]);
            #pragma unroll
            for (int i = 0; i < 4; ++i)
                #pragma unroll
                for (int j = 0; j < 4; ++j)
                    acc[i][j] = __builtin_amdgcn_mfma_f32_16x16x32_bf16(
                        af[i], bfr[j], acc[i][j], 0, 0, 0);
        }
    }
    float wtv[4];
    #pragma unroll
    for (int j = 0; j < 4; ++j) wtv[j] = Wt[n0 + wn + j * 16 + l15];
    #pragma unroll
    for (int i = 0; i < 4; ++i)
        #pragma unroll
        for (int rr = 0; rr < 4; ++rr) {
            const int mm = m0 + wm + i * 16 + q * 4 + rr;
            const int b2 = mm / 21;
            const int s2 = mm - b2 * 21;
            const float* wcrow = wc + (size_t)b2 * Hq + n0 + wn;
            const float* birow = bias + (size_t)s2 * Hq + n0 + wn;
            float part = 0.f;
            #pragma unroll
            for (int j = 0; j < 4; ++j) {
                const int nl = j * 16 + l15;
                float e = tanhf(acc[i][j][rr] + wcrow[nl] + birow[nl]);
                part += e * wtv[j];
            }
            part += __shfl_xor(part, 1);
            part += __shfl_xor(part, 2);
            part += __shfl_xor(part, 4);
            part += __shfl_xor(part, 8);
            if (l15 == 0) atomicAdd(&scores[mm], part);
        }
}

__global__ __launch_bounds__(256) void softmax_out_fb(
    const float* __restrict__ scores, const float* __restrict__ allh,
    float* __restrict__ out)
{
    const int b = blockIdx.x;
    const int t = threadIdx.x;
    float sc[Sq];
    float mx = -1e30f;
    #pragma unroll
    for (int s = 0; s < Sq; ++s) {
        sc[s] = scores[(size_t)b * Sq + s];
        mx = fmaxf(mx, sc[s]);
    }
    float sum = 0.f;
    #pragma unroll
    for (int s = 0; s < Sq; ++s) {
        sc[s] = __expf(sc[s] - mx);
        sum += sc[s];
    }
    const float inv = 1.0f / sum;
    for (int h = t; h < Hq; h += 256) {
        float acc = 0.f;
        #pragma unroll
        for (int s = 0; s < Sq; ++s)
            acc += sc[s] * allh[(size_t)s * (Bq * Hq) + (size_t)b * Hq + h];
        out[(size_t)b * Hq + h] = acc * inv;
    }
}

// ---------------------------------------------------------------------------
extern "C" void kernel_launch(void* const* d_in, const int* in_sizes, int n_in,
                              void* d_out, int out_size, void* d_ws, size_t ws_size,
                              hipStream_t stream) {
    const float* c    = (const float*)d_in[0];
    const float* allh = (const float*)d_in[1];
    const float* W    = (const float*)d_in[2];
    const float* V    = (const float*)d_in[3];
    const float* bias = (const float*)d_in[4];
    const float* Wt   = (const float*)d_in[5];
    float* out = (float*)d_out;
    char* ws = (char*)d_ws;

    const size_t NEED = 411041792ULL;  // ~392 MiB fast-path scratch

    if (ws_size >= NEED) {
        unsigned short* Vt  = (unsigned short*)ws;                 // 2 MB
        unsigned short* Wtr = (unsigned short*)(ws + 2097152);     // 2 MB
        float* wc           = (float*)(ws + 4194304);              // 32 MB
        float* scores       = (float*)(ws + 37748736);             // 688 KB
        unsigned short* cb  = (unsigned short*)(ws + 41943040);    // 16 MB
        unsigned short* hb  = (unsigned short*)(ws + 58720256);    // 336 MB

        hipMemsetAsync(scores, 0, (size_t)Bq * Sq * sizeof(float), stream);
        transpose_cvt<<<dim3(32, 32), dim3(32, 8), 0, stream>>>(W, Wtr);
        transpose_cvt<<<dim3(32, 32), dim3(32, 8), 0, stream>>>(V, Vt);
        cvt_bf16<<<1024, 256, 0, stream>>>(c, cb, Bq * Hq / 8);
        cvt_bf16<<<4096, 256, 0, stream>>>(allh, hb, Sq * (Bq / 8) * Hq);

        gemm_wc2<<<dim3(Hq / 128, Bq / 128), 256, 0, stream>>>(cb, Wtr, wc);
        gemm_scores256<<<dim3((Mq / 256) * (Hq / 256)), dim3(512), 0, stream>>>(
            hb, Vt, wc, bias, Wt, scores);
        softmax_out2<<<Bq, 256, 0, stream>>>(scores, hb, out);
    } else {
        unsigned short* Vt  = (unsigned short*)ws;
        unsigned short* Wtr = (unsigned short*)(ws + (2u << 20));
        float* wc     = (float*)(ws + (4u << 20));
        float* scores = (float*)(ws + (4u << 20) + (size_t)Bq * Hq * 4);

        hipMemsetAsync(scores, 0, (size_t)Bq * Sq * sizeof(float), stream);
        transpose_cvt<<<dim3(32, 32), dim3(32, 8), 0, stream>>>(W, Wtr);
        transpose_cvt<<<dim3(32, 32), dim3(32, 8), 0, stream>>>(V, Vt);
        gemm_wc_fb<<<dim3(Bq / 128, Hq / 128), 256, 0, stream>>>(c, Wtr, wc);
        gemm_scores_fb<<<dim3(Mq / 128, Hq / 128), 256, 0, stream>>>(
            allh, Vt, wc, bias, Wt, scores);
        softmax_out_fb<<<Bq, 256, 0, stream>>>(scores, allh, out);
    }
}

// Round 3
// 1724.990 us; speedup vs baseline: 1.7608x; 1.7587x over previous
//
#include <hip/hip_runtime.h>
#include <hip/hip_bf16.h>
#include <cstdint>
#include <cstddef>

#define Bq 8192
#define Sq 21
#define Hq 1024
#define Mq (Bq * Sq)   // 172032

typedef __attribute__((ext_vector_type(8))) short short8;
typedef __attribute__((ext_vector_type(4))) float floatx4;

__device__ __forceinline__ short f2b(float x) {
    // RNE float -> bf16 bits (finite inputs only)
    unsigned u = __builtin_bit_cast(unsigned, x);
    unsigned r = (u + 0x7fffu + ((u >> 16) & 1u)) >> 16;
    return (short)r;
}
__device__ __forceinline__ float b2f(unsigned short b) {
    return __builtin_bit_cast(float, (unsigned)b << 16);
}

// fast tanh: 1 - 2/(e^{2x}+1).  v_exp + v_rcp, exact at +-inf, |err|~1e-6.
__device__ __forceinline__ float fast_tanh(float x) {
    float e = __expf(2.0f * x);
    return fmaf(-2.0f, __builtin_amdgcn_rcpf(e + 1.0f), 1.0f);
}

// async global->LDS, 16B per lane; LDS dest = wave-uniform base + lane*16
__device__ __forceinline__ void gl_lds16(const void* g, void* l) {
    __builtin_amdgcn_global_load_lds(
        (const __attribute__((address_space(1))) unsigned int*)g,
        (__attribute__((address_space(3))) unsigned int*)l, 16, 0, 0);
}

// ---------------------------------------------------------------------------
// transpose + convert [K][N] fp32 -> [N][K] bf16
// ---------------------------------------------------------------------------
__global__ void transpose_cvt(const float* __restrict__ src,
                              unsigned short* __restrict__ dst) {
    __shared__ float tile[32][33];
    const int n0 = blockIdx.x * 32;
    const int k0 = blockIdx.y * 32;
    const int tx = threadIdx.x;
    const int ty = threadIdx.y;
    #pragma unroll
    for (int i = ty; i < 32; i += 8)
        tile[i][tx] = src[(size_t)(k0 + i) * Hq + n0 + tx];
    __syncthreads();
    #pragma unroll
    for (int i = ty; i < 32; i += 8)
        dst[(size_t)(n0 + i) * Hq + k0 + tx] = (unsigned short)f2b(tile[tx][i]);
}

// ---------------------------------------------------------------------------
// fp32 -> bf16 bulk convert (n8 = elements/8)
// ---------------------------------------------------------------------------
__global__ __launch_bounds__(256) void cvt_bf16(const float* __restrict__ src,
                                                unsigned short* __restrict__ dst,
                                                int n8) {
    int i = blockIdx.x * 256 + threadIdx.x;
    const int stride = gridDim.x * 256;
    for (; i < n8; i += stride) {
        const float4* s4 = reinterpret_cast<const float4*>(src) + (size_t)i * 2;
        float4 a = s4[0], b = s4[1];
        short8 p;
        p[0] = f2b(a.x); p[1] = f2b(a.y); p[2] = f2b(a.z); p[3] = f2b(a.w);
        p[4] = f2b(b.x); p[5] = f2b(b.y); p[6] = f2b(b.z); p[7] = f2b(b.w);
        reinterpret_cast<short8*>(dst)[i] = p;
    }
}

// ---------------------------------------------------------------------------
// m97-style GEMM: 128x128 tile, BK=64, bf16 A/B, global_load_lds staging,
// XOR-swizzled unpadded LDS.  Kernel A: wc = c @ W (stores fp32 wc).
// ---------------------------------------------------------------------------
__global__ __launch_bounds__(256, 3) void gemm_wc2(
    const unsigned short* __restrict__ cb, const unsigned short* __restrict__ Wtr,
    float* __restrict__ wc)
{
    __shared__ unsigned short As[128 * 64];
    __shared__ unsigned short Bs[128 * 64];

    const int n0 = blockIdx.x * 128;
    const int m0 = blockIdx.y * 128;
    const int t = threadIdx.x;
    const int lane = t & 63;
    const int w = t >> 6;

    const int sub = lane >> 3;          // 0..7
    const int k8g = (lane & 7) ^ sub;   // swizzled source k-chunk
    const unsigned short* ap[4];
    const unsigned short* bp[4];
    #pragma unroll
    for (int j = 0; j < 4; ++j) {
        const int r = w * 32 + j * 8 + sub;
        ap[j] = cb + (size_t)(m0 + r) * Hq + k8g * 8;
        bp[j] = Wtr + (size_t)(n0 + r) * Hq + k8g * 8;
    }

    const int wm = (w & 1) * 64;
    const int wn = (w >> 1) * 64;
    const int l15 = lane & 15;
    const int q = lane >> 4;
    const int sw = l15 & 7;

    floatx4 acc[4][4] = {};
    const short8* AsV = (const short8*)As;
    const short8* BsV = (const short8*)Bs;

    for (int k0 = 0; k0 < Hq; k0 += 64) {
        __syncthreads();
        #pragma unroll
        for (int j = 0; j < 4; ++j) {
            gl_lds16(ap[j] + k0, &As[(w * 256 + j * 64) * 8]);
            gl_lds16(bp[j] + k0, &Bs[(w * 256 + j * 64) * 8]);
        }
        __syncthreads();
        #pragma unroll
        for (int kk = 0; kk < 2; ++kk) {
            const int k8 = kk * 4 + q;
            short8 af[4], bfr[4];
            #pragma unroll
            for (int i = 0; i < 4; ++i) {
                af[i]  = AsV[((wm + i * 16 + l15) << 3) | (k8 ^ sw)];
                bfr[i] = BsV[((wn + i * 16 + l15) << 3) | (k8 ^ sw)];
            }
            #pragma unroll
            for (int i = 0; i < 4; ++i)
                #pragma unroll
                for (int j = 0; j < 4; ++j)
                    acc[i][j] = __builtin_amdgcn_mfma_f32_16x16x32_bf16(
                        af[i], bfr[j], acc[i][j], 0, 0, 0);
        }
    }

    #pragma unroll
    for (int i = 0; i < 4; ++i)
        #pragma unroll
        for (int rr = 0; rr < 4; ++rr) {
            const int mm = m0 + wm + i * 16 + q * 4 + rr;
            #pragma unroll
            for (int j = 0; j < 4; ++j) {
                const int nn = n0 + wn + j * 16 + l15;
                wc[(size_t)mm * Hq + nn] = acc[i][j][rr];
            }
        }
}

// ---------------------------------------------------------------------------
// Kernel B (round-3): 128x128 tile, 4 waves (256 thr), DOUBLE-BUFFERED
// single-barrier pipeline: stage(next) -> compute(cur) -> __syncthreads().
// Geometry identical to the proven round-0 kernel (VGPR 72, no spill);
// 512-thread variants are structurally capped at 256 VGPR/wave (8 waves on
// 4 SIMDs) and spilled the 128-reg accumulator -> 3.4 GB scratch traffic.
// LDS: 2 bufs x (A 128x64 + B 128x64) bf16 = 64 KiB -> 2 blocks/CU.
// ---------------------------------------------------------------------------
__device__ __forceinline__ void stage128(
    unsigned short* __restrict__ bufA, int w,
    const unsigned short* const (&ap)[4], const unsigned short* const (&bp)[4],
    int k0)
{
    unsigned short* dstA = bufA + w * 2048;          // wave w: rows w*32..+31
    unsigned short* dstB = bufA + 8192 + w * 2048;
    #pragma unroll
    for (int j = 0; j < 4; ++j) {
        gl_lds16(ap[j] + k0, dstA + j * 512);        // 8 rows / wave-load
        gl_lds16(bp[j] + k0, dstB + j * 512);
    }
}

__device__ __forceinline__ void compute128(
    const unsigned short* __restrict__ bufA,
    floatx4 (&acc)[4][4], int wm, int wn, int l15, int q, int sw)
{
    const short8* AsV = (const short8*)bufA;
    const short8* BsV = (const short8*)(bufA + 8192);
    #pragma unroll
    for (int kk = 0; kk < 2; ++kk) {
        const int k8 = kk * 4 + q;
        short8 af[4], bfr[4];
        #pragma unroll
        for (int i = 0; i < 4; ++i) {
            af[i]  = AsV[((wm + i * 16 + l15) << 3) | (k8 ^ sw)];
            bfr[i] = BsV[((wn + i * 16 + l15) << 3) | (k8 ^ sw)];
        }
        #pragma unroll
        for (int i = 0; i < 4; ++i)
            #pragma unroll
            for (int j = 0; j < 4; ++j)
                acc[i][j] = __builtin_amdgcn_mfma_f32_16x16x32_bf16(
                    af[i], bfr[j], acc[i][j], 0, 0, 0);
    }
}

__global__ __launch_bounds__(256, 2) void gemm_scores128db(
    const unsigned short* __restrict__ hb, const unsigned short* __restrict__ Vt,
    const float* __restrict__ wc, const float* __restrict__ bias,
    const float* __restrict__ Wt, float* __restrict__ scores)
{
    __shared__ unsigned short lds[32768];   // [2 buf][A|B][128*64] = 64 KiB

    // XCD-chunked bijective swizzle: 10752 blocks, 10752 % 8 == 0.
    // XCD x gets contiguous m-panels [x*168, (x+1)*168); n fastest within.
    const int orig = blockIdx.x;
    const int swz = (orig & 7) * 1344 + (orig >> 3);
    const int n0 = (swz & 7) * 128;
    const int m0 = (swz >> 3) * 128;

    const int t = threadIdx.x;
    const int lane = t & 63;
    const int w = t >> 6;                 // 0..3

    const int sub = lane >> 3;            // row within 8-row group
    const int k8g = (lane & 7) ^ sub;     // pre-swizzled source k-chunk
    const unsigned short* ap[4];
    const unsigned short* bp[4];
    #pragma unroll
    for (int j = 0; j < 4; ++j) {
        const int r = w * 32 + j * 8 + sub;
        const int m = m0 + r;
        const int bb = m / 21;
        const int ss = m - bb * 21;
        ap[j] = hb + ((size_t)ss * Bq + bb) * Hq + k8g * 8;
        bp[j] = Vt + (size_t)(n0 + r) * Hq + k8g * 8;
    }

    const int wm = (w & 1) * 64;
    const int wn = (w >> 1) * 64;
    const int l15 = lane & 15;
    const int q = lane >> 4;
    const int sw = l15 & 7;

    floatx4 acc[4][4] = {};

    unsigned short* buf0 = lds;
    unsigned short* buf1 = lds + 16384;

    // prologue: fill buf0 with K-tile 0
    stage128(buf0, w, ap, bp, 0);
    __syncthreads();

    // 16 K-steps as 8 statically-addressed pairs; one barrier per step.
    // stage(next) issues before compute(cur) so the 8 global_load_lds of
    // the next tile fly under 32 MFMA; the barrier drains both counters.
    #pragma unroll 1
    for (int tt = 0; tt < 8; ++tt) {
        stage128(buf1, w, ap, bp, tt * 128 + 64);
        compute128(buf0, acc, wm, wn, l15, q, sw);
        __syncthreads();
        if (tt < 7) {
            stage128(buf0, w, ap, bp, tt * 128 + 128);
            compute128(buf1, acc, wm, wn, l15, q, sw);
            __syncthreads();
        } else {
            compute128(buf1, acc, wm, wn, l15, q, sw);  // last tile
        }
    }

    // epilogue: e = tanh(acc + wc[b] + bias[s]); scores += e . Wt
    float wtv[4];
    #pragma unroll
    for (int j = 0; j < 4; ++j) wtv[j] = Wt[n0 + wn + j * 16 + l15];

    #pragma unroll
    for (int i = 0; i < 4; ++i) {
        #pragma unroll
        for (int rr = 0; rr < 4; ++rr) {
            const int mm = m0 + wm + i * 16 + q * 4 + rr;
            const int b2 = mm / 21;
            const int s2 = mm - b2 * 21;
            const float* wcrow = wc + (size_t)b2 * Hq + n0 + wn;
            const float* birow = bias + (size_t)s2 * Hq + n0 + wn;
            float part = 0.f;
            #pragma unroll
            for (int j = 0; j < 4; ++j) {
                const int nl = j * 16 + l15;
                float e = fast_tanh(acc[i][j][rr] + wcrow[nl] + birow[nl]);
                part += e * wtv[j];
            }
            part += __shfl_xor(part, 1);
            part += __shfl_xor(part, 2);
            part += __shfl_xor(part, 4);
            part += __shfl_xor(part, 8);
            if (l15 == 0) atomicAdd(&scores[mm], part);
        }
    }
}

// ---------------------------------------------------------------------------
// softmax over S=21 + y[b,:] = sum_s alpha_s h[s,b,:]  (bf16 h)
// ---------------------------------------------------------------------------
__global__ __launch_bounds__(256) void softmax_out2(
    const float* __restrict__ scores, const unsigned short* __restrict__ hb,
    float* __restrict__ out)
{
    const int b = blockIdx.x;
    const int t = threadIdx.x;

    float sc[Sq];
    float mx = -1e30f;
    #pragma unroll
    for (int s = 0; s < Sq; ++s) {
        sc[s] = scores[(size_t)b * Sq + s];
        mx = fmaxf(mx, sc[s]);
    }
    float sum = 0.f;
    #pragma unroll
    for (int s = 0; s < Sq; ++s) {
        sc[s] = __expf(sc[s] - mx);
        sum += sc[s];
    }
    const float inv = 1.0f / sum;

    const int h = t * 4;
    float a0 = 0.f, a1 = 0.f, a2 = 0.f, a3 = 0.f;
    #pragma unroll
    for (int s = 0; s < Sq; ++s) {
        const unsigned short* p = hb + ((size_t)s * Bq + b) * Hq + h;
        uint2 u = *reinterpret_cast<const uint2*>(p);
        a0 += sc[s] * b2f((unsigned short)(u.x & 0xffffu));
        a1 += sc[s] * b2f((unsigned short)(u.x >> 16));
        a2 += sc[s] * b2f((unsigned short)(u.y & 0xffffu));
        a3 += sc[s] * b2f((unsigned short)(u.y >> 16));
    }
    float4 r;
    r.x = a0 * inv; r.y = a1 * inv; r.z = a2 * inv; r.w = a3 * inv;
    *reinterpret_cast<float4*>(out + (size_t)b * Hq + h) = r;
}

// ===========================================================================
// Fallback path (round-1, needs only ~38 MB ws) — used if ws_size too small.
// ===========================================================================
__global__ __launch_bounds__(256, 2) void gemm_wc_fb(
    const float* __restrict__ c, const unsigned short* __restrict__ Wtr,
    float* __restrict__ wc)
{
    __shared__ short As[128][72];
    __shared__ short Bs[128][72];
    const int m0 = blockIdx.x * 128;
    const int n0 = blockIdx.y * 128;
    const int t = threadIdx.x;
    const int r = t >> 1;
    const int half = t & 1;
    const float*          arow = c + (size_t)(m0 + r) * Hq + half * 32;
    const unsigned short* brow = Wtr + (size_t)(n0 + r) * Hq + half * 32;
    const int lane = t & 63;
    const int w = t >> 6;
    const int wm = (w & 1) * 64;
    const int wn = (w >> 1) * 64;
    const int l15 = lane & 15;
    const int q = lane >> 4;
    floatx4 acc[4][4] = {};
    for (int k0 = 0; k0 < Hq; k0 += 64) {
        __syncthreads();
        const float4* a4 = reinterpret_cast<const float4*>(arow + k0);
        #pragma unroll
        for (int i = 0; i < 4; ++i) {
            float4 v0 = a4[2 * i], v1 = a4[2 * i + 1];
            short8 p;
            p[0] = f2b(v0.x); p[1] = f2b(v0.y); p[2] = f2b(v0.z); p[3] = f2b(v0.w);
            p[4] = f2b(v1.x); p[5] = f2b(v1.y); p[6] = f2b(v1.z); p[7] = f2b(v1.w);
            *reinterpret_cast<short8*>(&As[r][half * 32 + i * 8]) = p;
        }
        const short8* b8 = reinterpret_cast<const short8*>(brow + k0);
        #pragma unroll
        for (int i = 0; i < 4; ++i)
            *reinterpret_cast<short8*>(&Bs[r][half * 32 + i * 8]) = b8[i];
        __syncthreads();
        #pragma unroll
        for (int kk = 0; kk < 64; kk += 32) {
            short8 af[4], bfr[4];
            #pragma unroll
            for (int i = 0; i < 4; ++i)
                af[i] = *reinterpret_cast<const short8*>(&As[wm + i * 16 + l15][kk + q * 8]);
            #pragma unroll
            for (int j = 0; j < 4; ++j)
                bfr[j] = *reinterpret_cast<const short8*>(&Bs[wn + j * 16 + l15][kk + q * 8]);
            #pragma unroll
            for (int i = 0; i < 4; ++i)
                #pragma unroll
                for (int j = 0; j < 4; ++j)
                    acc[i][j] = __builtin_amdgcn_mfma_f32_16x16x32_bf16(
                        af[i], bfr[j], acc[i][j], 0, 0, 0);
        }
    }
    #pragma unroll
    for (int i = 0; i < 4; ++i)
        #pragma unroll
        for (int rr = 0; rr < 4; ++rr) {
            const int mm = m0 + wm + i * 16 + q * 4 + rr;
            #pragma unroll
            for (int j = 0; j < 4; ++j)
                wc[(size_t)mm * Hq + n0 + wn + j * 16 + l15] = acc[i][j][rr];
        }
}

__global__ __launch_bounds__(256, 2) void gemm_scores_fb(
    const float* __restrict__ allh, const unsigned short* __restrict__ Vt,
    const float* __restrict__ wc, const float* __restrict__ bias,
    const float* __restrict__ Wt, float* __restrict__ scores)
{
    __shared__ short As[128][72];
    __shared__ short Bs[128][72];
    const int m0 = blockIdx.x * 128;
    const int n0 = blockIdx.y * 128;
    const int t = threadIdx.x;
    const int r = t >> 1;
    const int half = t & 1;
    const int m = m0 + r;
    const int bb = m / 21;
    const int ss = m - bb * 21;
    const float* arow = allh + (size_t)ss * (Bq * Hq) + (size_t)bb * Hq + half * 32;
    const unsigned short* brow = Vt + (size_t)(n0 + r) * Hq + half * 32;
    const int lane = t & 63;
    const int w = t >> 6;
    const int wm = (w & 1) * 64;
    const int wn = (w >> 1) * 64;
    const int l15 = lane & 15;
    const int q = lane >> 4;
    floatx4 acc[4][4] = {};
    for (int k0 = 0; k0 < Hq; k0 += 64) {
        __syncthreads();
        const float4* a4 = reinterpret_cast<const float4*>(arow + k0);
        #pragma unroll
        for (int i = 0; i < 4; ++i) {
            float4 v0 = a4[2 * i], v1 = a4[2 * i + 1];
            short8 p;
            p[0] = f2b(v0.x); p[1] = f2b(v0.y); p[2] = f2b(v0.z); p[3] = f2b(v0.w);
            p[4] = f2b(v1.x); p[5] = f2b(v1.y); p[6] = f2b(v1.z); p[7] = f2b(v1.w);
            *reinterpret_cast<short8*>(&As[r][half * 32 + i * 8]) = p;
        }
        const short8* b8 = reinterpret_cast<const short8*>(brow + k0);
        #pragma unroll
        for (int i = 0; i < 4; ++i)
            *reinterpret_cast<short8*>(&Bs[r][half * 32 + i * 8]) = b8[i];
        __syncthreads();
        #pragma unroll
        for (int kk = 0; kk < 64; kk += 32) {
            short8 af[4], bfr[4];
            #pragma unroll
            for (int i = 0; i < 4; ++i)
                af[i] = *reinterpret_cast<const short8*>(&As[wm + i * 16 + l15][kk + q * 8]);
            #pragma unroll
            for (int j = 0; j < 4; ++j)
                bfr[j] = *reinterpret_cast<const short8*>(&Bs[wn + j * 16 + l15][kk + q * 8]);
            #pragma unroll
            for (int i = 0; i < 4; ++i)
                #pragma unroll
                for (int j = 0; j < 4; ++j)
                    acc[i][j] = __builtin_amdgcn_mfma_f32_16x16x32_bf16(
                        af[i], bfr[j], acc[i][j], 0, 0, 0);
        }
    }
    float wtv[4];
    #pragma unroll
    for (int j = 0; j < 4; ++j) wtv[j] = Wt[n0 + wn + j * 16 + l15];
    #pragma unroll
    for (int i = 0; i < 4; ++i)
        #pragma unroll
        for (int rr = 0; rr < 4; ++rr) {
            const int mm = m0 + wm + i * 16 + q * 4 + rr;
            const int b2 = mm / 21;
            const int s2 = mm - b2 * 21;
            const float* wcrow = wc + (size_t)b2 * Hq + n0 + wn;
            const float* birow = bias + (size_t)s2 * Hq + n0 + wn;
            float part = 0.f;
            #pragma unroll
            for (int j = 0; j < 4; ++j) {
                const int nl = j * 16 + l15;
                float e = tanhf(acc[i][j][rr] + wcrow[nl] + birow[nl]);
                part += e * wtv[j];
            }
            part += __shfl_xor(part, 1);
            part += __shfl_xor(part, 2);
            part += __shfl_xor(part, 4);
            part += __shfl_xor(part, 8);
            if (l15 == 0) atomicAdd(&scores[mm], part);
        }
}

__global__ __launch_bounds__(256) void softmax_out_fb(
    const float* __restrict__ scores, const float* __restrict__ allh,
    float* __restrict__ out)
{
    const int b = blockIdx.x;
    const int t = threadIdx.x;
    float sc[Sq];
    float mx = -1e30f;
    #pragma unroll
    for (int s = 0; s < Sq; ++s) {
        sc[s] = scores[(size_t)b * Sq + s];
        mx = fmaxf(mx, sc[s]);
    }
    float sum = 0.f;
    #pragma unroll
    for (int s = 0; s < Sq; ++s) {
        sc[s] = __expf(sc[s] - mx);
        sum += sc[s];
    }
    const float inv = 1.0f / sum;
    for (int h = t; h < Hq; h += 256) {
        float acc = 0.f;
        #pragma unroll
        for (int s = 0; s < Sq; ++s)
            acc += sc[s] * allh[(size_t)s * (Bq * Hq) + (size_t)b * Hq + h];
        out[(size_t)b * Hq + h] = acc * inv;
    }
}

// ---------------------------------------------------------------------------
extern "C" void kernel_launch(void* const* d_in, const int* in_sizes, int n_in,
                              void* d_out, int out_size, void* d_ws, size_t ws_size,
                              hipStream_t stream) {
    const float* c    = (const float*)d_in[0];
    const float* allh = (const float*)d_in[1];
    const float* W    = (const float*)d_in[2];
    const float* V    = (const float*)d_in[3];
    const float* bias = (const float*)d_in[4];
    const float* Wt   = (const float*)d_in[5];
    float* out = (float*)d_out;
    char* ws = (char*)d_ws;

    const size_t NEED = 411041792ULL;  // ~392 MiB fast-path scratch

    if (ws_size >= NEED) {
        unsigned short* Vt  = (unsigned short*)ws;                 // 2 MB
        unsigned short* Wtr = (unsigned short*)(ws + 2097152);     // 2 MB
        float* wc           = (float*)(ws + 4194304);              // 32 MB
        float* scores       = (float*)(ws + 37748736);             // 688 KB
        unsigned short* cb  = (unsigned short*)(ws + 41943040);    // 16 MB
        unsigned short* hb  = (unsigned short*)(ws + 58720256);    // 336 MB

        hipMemsetAsync(scores, 0, (size_t)Bq * Sq * sizeof(float), stream);
        transpose_cvt<<<dim3(32, 32), dim3(32, 8), 0, stream>>>(W, Wtr);
        transpose_cvt<<<dim3(32, 32), dim3(32, 8), 0, stream>>>(V, Vt);
        cvt_bf16<<<1024, 256, 0, stream>>>(c, cb, Bq * Hq / 8);
        cvt_bf16<<<4096, 256, 0, stream>>>(allh, hb, Sq * (Bq / 8) * Hq);

        gemm_wc2<<<dim3(Hq / 128, Bq / 128), 256, 0, stream>>>(cb, Wtr, wc);
        gemm_scores128db<<<dim3((Mq / 128) * (Hq / 128)), 256, 0, stream>>>(
            hb, Vt, wc, bias, Wt, scores);
        softmax_out2<<<Bq, 256, 0, stream>>>(scores, hb, out);
    } else {
        unsigned short* Vt  = (unsigned short*)ws;
        unsigned short* Wtr = (unsigned short*)(ws + (2u << 20));
        float* wc     = (float*)(ws + (4u << 20));
        float* scores = (float*)(ws + (4u << 20) + (size_t)Bq * Hq * 4);

        hipMemsetAsync(scores, 0, (size_t)Bq * Sq * sizeof(float), stream);
        transpose_cvt<<<dim3(32, 32), dim3(32, 8), 0, stream>>>(W, Wtr);
        transpose_cvt<<<dim3(32, 32), dim3(32, 8), 0, stream>>>(V, Vt);
        gemm_wc_fb<<<dim3(Bq / 128, Hq / 128), 256, 0, stream>>>(c, Wtr, wc);
        gemm_scores_fb<<<dim3(Mq / 128, Hq / 128), 256, 0, stream>>>(
            allh, Vt, wc, bias, Wt, scores);
        softmax_out_fb<<<Bq, 256, 0, stream>>>(scores, allh, out);
    }
}

// Round 4
// 1646.907 us; speedup vs baseline: 1.8443x; 1.0474x over previous
//
#include <hip/hip_runtime.h>
#include <hip/hip_bf16.h>
#include <cstdint>
#include <cstddef>

#define Bq 8192
#define Sq 21
#define Hq 1024
#define Mq (Bq * Sq)   // 172032

typedef __attribute__((ext_vector_type(8))) short short8;
typedef __attribute__((ext_vector_type(4))) float floatx4;

__device__ __forceinline__ short f2b(float x) {
    // RNE float -> bf16 bits (finite inputs only)
    unsigned u = __builtin_bit_cast(unsigned, x);
    unsigned r = (u + 0x7fffu + ((u >> 16) & 1u)) >> 16;
    return (short)r;
}
__device__ __forceinline__ float b2f(unsigned short b) {
    return __builtin_bit_cast(float, (unsigned)b << 16);
}

// fast tanh: 1 - 2/(e^{2x}+1).  v_exp + v_rcp, exact at +-inf, |err|~1e-6.
__device__ __forceinline__ float fast_tanh(float x) {
    float e = __expf(2.0f * x);
    return fmaf(-2.0f, __builtin_amdgcn_rcpf(e + 1.0f), 1.0f);
}

// async global->LDS, 16B per lane; LDS dest = wave-uniform base + lane*16
__device__ __forceinline__ void gl_lds16(const void* g, void* l) {
    __builtin_amdgcn_global_load_lds(
        (const __attribute__((address_space(1))) unsigned int*)g,
        (__attribute__((address_space(3))) unsigned int*)l, 16, 0, 0);
}

// ---------------------------------------------------------------------------
// transpose + convert [K][N] fp32 -> [N][K] bf16
// ---------------------------------------------------------------------------
__global__ void transpose_cvt(const float* __restrict__ src,
                              unsigned short* __restrict__ dst) {
    __shared__ float tile[32][33];
    const int n0 = blockIdx.x * 32;
    const int k0 = blockIdx.y * 32;
    const int tx = threadIdx.x;
    const int ty = threadIdx.y;
    #pragma unroll
    for (int i = ty; i < 32; i += 8)
        tile[i][tx] = src[(size_t)(k0 + i) * Hq + n0 + tx];
    __syncthreads();
    #pragma unroll
    for (int i = ty; i < 32; i += 8)
        dst[(size_t)(n0 + i) * Hq + k0 + tx] = (unsigned short)f2b(tile[tx][i]);
}

// ---------------------------------------------------------------------------
// fp32 -> bf16 bulk convert (n8 = elements/8)
// ---------------------------------------------------------------------------
__global__ __launch_bounds__(256) void cvt_bf16(const float* __restrict__ src,
                                                unsigned short* __restrict__ dst,
                                                int n8) {
    int i = blockIdx.x * 256 + threadIdx.x;
    const int stride = gridDim.x * 256;
    for (; i < n8; i += stride) {
        const float4* s4 = reinterpret_cast<const float4*>(src) + (size_t)i * 2;
        float4 a = s4[0], b = s4[1];
        short8 p;
        p[0] = f2b(a.x); p[1] = f2b(a.y); p[2] = f2b(a.z); p[3] = f2b(a.w);
        p[4] = f2b(b.x); p[5] = f2b(b.y); p[6] = f2b(b.z); p[7] = f2b(b.w);
        reinterpret_cast<short8*>(dst)[i] = p;
    }
}

// ---------------------------------------------------------------------------
// m97-style GEMM: 128x128 tile, BK=64, bf16 A/B, global_load_lds staging,
// XOR-swizzled unpadded LDS.  Kernel A: wc = c @ W (stores fp32 wc).
// ---------------------------------------------------------------------------
__global__ __launch_bounds__(256, 3) void gemm_wc2(
    const unsigned short* __restrict__ cb, const unsigned short* __restrict__ Wtr,
    float* __restrict__ wc)
{
    __shared__ unsigned short As[128 * 64];
    __shared__ unsigned short Bs[128 * 64];

    const int n0 = blockIdx.x * 128;
    const int m0 = blockIdx.y * 128;
    const int t = threadIdx.x;
    const int lane = t & 63;
    const int w = t >> 6;

    const int sub = lane >> 3;          // 0..7
    const int k8g = (lane & 7) ^ sub;   // swizzled source k-chunk
    const unsigned short* ap[4];
    const unsigned short* bp[4];
    #pragma unroll
    for (int j = 0; j < 4; ++j) {
        const int r = w * 32 + j * 8 + sub;
        ap[j] = cb + (size_t)(m0 + r) * Hq + k8g * 8;
        bp[j] = Wtr + (size_t)(n0 + r) * Hq + k8g * 8;
    }

    const int wm = (w & 1) * 64;
    const int wn = (w >> 1) * 64;
    const int l15 = lane & 15;
    const int q = lane >> 4;
    const int sw = l15 & 7;

    floatx4 acc[4][4] = {};
    const short8* AsV = (const short8*)As;
    const short8* BsV = (const short8*)Bs;

    for (int k0 = 0; k0 < Hq; k0 += 64) {
        __syncthreads();
        #pragma unroll
        for (int j = 0; j < 4; ++j) {
            gl_lds16(ap[j] + k0, &As[(w * 256 + j * 64) * 8]);
            gl_lds16(bp[j] + k0, &Bs[(w * 256 + j * 64) * 8]);
        }
        __syncthreads();
        #pragma unroll
        for (int kk = 0; kk < 2; ++kk) {
            const int k8 = kk * 4 + q;
            short8 af[4], bfr[4];
            #pragma unroll
            for (int i = 0; i < 4; ++i) {
                af[i]  = AsV[((wm + i * 16 + l15) << 3) | (k8 ^ sw)];
                bfr[i] = BsV[((wn + i * 16 + l15) << 3) | (k8 ^ sw)];
            }
            #pragma unroll
            for (int i = 0; i < 4; ++i)
                #pragma unroll
                for (int j = 0; j < 4; ++j)
                    acc[i][j] = __builtin_amdgcn_mfma_f32_16x16x32_bf16(
                        af[i], bfr[j], acc[i][j], 0, 0, 0);
        }
    }

    #pragma unroll
    for (int i = 0; i < 4; ++i)
        #pragma unroll
        for (int rr = 0; rr < 4; ++rr) {
            const int mm = m0 + wm + i * 16 + q * 4 + rr;
            #pragma unroll
            for (int j = 0; j < 4; ++j) {
                const int nn = n0 + wn + j * 16 + l15;
                wc[(size_t)mm * Hq + nn] = acc[i][j][rr];
            }
        }
}

// ---------------------------------------------------------------------------
// Kernel B (round-4): BM=128 x BN=256 x BK=64, 512 thr (8 waves 2Mx4N),
// per-wave 64x64 output (acc[4][4] = 64 VGPR).  THREE LDS buffers (48 KiB
// each, 144 KiB total, 1 block/CU) with a depth-2-ahead counted-vmcnt
// pipeline: per step {vmcnt(6); raw s_barrier; stage(T+2); compute(T)}.
// Loads get ~2 full K-steps of latency budget and the VMEM queue never
// drains (T4: never vmcnt(0) in the main loop).
// Safety: the per-step barrier separates (a) all waves' ds_reads of tile
// T-1 (consumed pre-barrier via lgkmcnt) from the stage overwriting that
// buffer, and (b) each wave's vmcnt wait from other waves' ds_reads.
// ---------------------------------------------------------------------------
__device__ __forceinline__ void stage_p3(
    unsigned short* __restrict__ buf, int w,
    const unsigned short* const (&gA)[2], const unsigned short* const (&gB)[4],
    int koff)
{
    // A: 128x64 bf16 at buf[0..8191]; B: 256x64 at buf[8192..24575]
    #pragma unroll
    for (int c = 0; c < 2; ++c)
        gl_lds16(gA[c] + koff, buf + c * 4096 + w * 512);
    #pragma unroll
    for (int c = 0; c < 4; ++c)
        gl_lds16(gB[c] + koff, buf + 8192 + c * 4096 + w * 512);
}

__device__ __forceinline__ void compute_p3(
    const unsigned short* __restrict__ buf,
    floatx4 (&acc)[4][4], int wm, int wn, int l15, int q, int sw)
{
    const short8* AsV = (const short8*)buf;            // 128 rows
    const short8* BsV = (const short8*)(buf + 8192);   // 256 rows
    #pragma unroll
    for (int kk = 0; kk < 2; ++kk) {
        const int k8 = kk * 4 + q;
        short8 af[4], bfr[4];
        #pragma unroll
        for (int i = 0; i < 4; ++i) {
            af[i]  = AsV[((wm + i * 16 + l15) << 3) | (k8 ^ sw)];
            bfr[i] = BsV[((wn + i * 16 + l15) << 3) | (k8 ^ sw)];
        }
        __builtin_amdgcn_s_setprio(1);
        #pragma unroll
        for (int i = 0; i < 4; ++i)
            #pragma unroll
            for (int j = 0; j < 4; ++j)
                acc[i][j] = __builtin_amdgcn_mfma_f32_16x16x32_bf16(
                    af[i], bfr[j], acc[i][j], 0, 0, 0);
        __builtin_amdgcn_s_setprio(0);
    }
}

__global__ __launch_bounds__(512, 1) void gemm_scores_p3(
    const unsigned short* __restrict__ hb, const unsigned short* __restrict__ Vt,
    const float* __restrict__ wc, const float* __restrict__ bias,
    const float* __restrict__ Wt, float* __restrict__ scores)
{
    __shared__ unsigned short lds[73728];   // 3 bufs x (A 128x64 + B 256x64)

    // XCD-chunked bijective swizzle: 5376 blocks, 5376 % 8 == 0.
    const int orig = blockIdx.x;
    const int swz = (orig & 7) * 672 + (orig >> 3);
    const int n0 = (swz & 3) * 256;
    const int m0 = (swz >> 2) * 128;

    const int t = threadIdx.x;
    const int lane = t & 63;
    const int w = t >> 6;                 // 0..7

    // staging source addresses: thread t covers row (t>>3) of each 64-row
    // call, chunk (t&7); XOR-pre-swizzled source chunk keeps LDS linear.
    const int rr0 = t >> 3;               // 0..63
    const int csrc = (t & 7) ^ (rr0 & 7);
    const unsigned short* gA[2];
    const unsigned short* gB[4];
    #pragma unroll
    for (int c = 0; c < 2; ++c) {
        const int m = m0 + c * 64 + rr0;
        const int bb = m / 21;
        const int ss = m - bb * 21;
        gA[c] = hb + ((size_t)ss * Bq + bb) * Hq + csrc * 8;
    }
    #pragma unroll
    for (int c = 0; c < 4; ++c)
        gB[c] = Vt + (size_t)(n0 + c * 64 + rr0) * Hq + csrc * 8;

    // wave tile: 2(M) x 4(N); per-wave output 64x64
    const int wm = (w >> 2) * 64;
    const int wn = (w & 3) * 64;
    const int l15 = lane & 15;
    const int q = lane >> 4;
    const int sw = l15 & 7;

    floatx4 acc[4][4] = {};

    unsigned short* b0 = lds;
    unsigned short* b1 = lds + 24576;
    unsigned short* b2 = lds + 49152;

    // prologue: tiles 0 and 1 in flight (12 loads/thread outstanding)
    stage_p3(b0, w, gA, gB, 0);
    stage_p3(b1, w, gA, gB, 64);

    #pragma unroll 1
    for (int T = 0; T < 14; ++T) {
        asm volatile("s_waitcnt vmcnt(6)" ::: "memory");  // tile T landed
        __builtin_amdgcn_s_barrier();
        __builtin_amdgcn_sched_barrier(0);
        stage_p3(b2, w, gA, gB, T * 64 + 128);            // tile T+2
        compute_p3(b0, acc, wm, wn, l15, q, sw);          // tile T
        unsigned short* tmp = b0; b0 = b1; b1 = b2; b2 = tmp;
    }
    // T = 14: no more staging
    asm volatile("s_waitcnt vmcnt(6)" ::: "memory");
    __builtin_amdgcn_s_barrier();
    __builtin_amdgcn_sched_barrier(0);
    compute_p3(b0, acc, wm, wn, l15, q, sw);
    { unsigned short* tmp = b0; b0 = b1; b1 = b2; b2 = tmp; }
    // T = 15: final tile, drain
    asm volatile("s_waitcnt vmcnt(0)" ::: "memory");
    __builtin_amdgcn_s_barrier();
    __builtin_amdgcn_sched_barrier(0);
    compute_p3(b0, acc, wm, wn, l15, q, sw);

    // epilogue: e = tanh(acc + wc[b] + bias[s]); scores += e . Wt
    float wtv[4];
    #pragma unroll
    for (int j = 0; j < 4; ++j) wtv[j] = Wt[n0 + wn + j * 16 + l15];

    #pragma unroll
    for (int i = 0; i < 4; ++i) {
        #pragma unroll
        for (int rr = 0; rr < 4; ++rr) {
            const int mm = m0 + wm + i * 16 + q * 4 + rr;
            const int b2i = mm / 21;
            const int s2 = mm - b2i * 21;
            const float* wcrow = wc + (size_t)b2i * Hq + n0 + wn;
            const float* birow = bias + (size_t)s2 * Hq + n0 + wn;
            float part = 0.f;
            #pragma unroll
            for (int j = 0; j < 4; ++j) {
                const int nl = j * 16 + l15;
                float e = fast_tanh(acc[i][j][rr] + wcrow[nl] + birow[nl]);
                part += e * wtv[j];
            }
            part += __shfl_xor(part, 1);
            part += __shfl_xor(part, 2);
            part += __shfl_xor(part, 4);
            part += __shfl_xor(part, 8);
            if (l15 == 0) atomicAdd(&scores[mm], part);
        }
    }
}

// ---------------------------------------------------------------------------
// softmax over S=21 + y[b,:] = sum_s alpha_s h[s,b,:]  (bf16 h)
// ---------------------------------------------------------------------------
__global__ __launch_bounds__(256) void softmax_out2(
    const float* __restrict__ scores, const unsigned short* __restrict__ hb,
    float* __restrict__ out)
{
    const int b = blockIdx.x;
    const int t = threadIdx.x;

    float sc[Sq];
    float mx = -1e30f;
    #pragma unroll
    for (int s = 0; s < Sq; ++s) {
        sc[s] = scores[(size_t)b * Sq + s];
        mx = fmaxf(mx, sc[s]);
    }
    float sum = 0.f;
    #pragma unroll
    for (int s = 0; s < Sq; ++s) {
        sc[s] = __expf(sc[s] - mx);
        sum += sc[s];
    }
    const float inv = 1.0f / sum;

    const int h = t * 4;
    float a0 = 0.f, a1 = 0.f, a2 = 0.f, a3 = 0.f;
    #pragma unroll
    for (int s = 0; s < Sq; ++s) {
        const unsigned short* p = hb + ((size_t)s * Bq + b) * Hq + h;
        uint2 u = *reinterpret_cast<const uint2*>(p);
        a0 += sc[s] * b2f((unsigned short)(u.x & 0xffffu));
        a1 += sc[s] * b2f((unsigned short)(u.x >> 16));
        a2 += sc[s] * b2f((unsigned short)(u.y & 0xffffu));
        a3 += sc[s] * b2f((unsigned short)(u.y >> 16));
    }
    float4 r;
    r.x = a0 * inv; r.y = a1 * inv; r.z = a2 * inv; r.w = a3 * inv;
    *reinterpret_cast<float4*>(out + (size_t)b * Hq + h) = r;
}

// ===========================================================================
// Fallback path (round-1, needs only ~38 MB ws) — used if ws_size too small.
// ===========================================================================
__global__ __launch_bounds__(256, 2) void gemm_wc_fb(
    const float* __restrict__ c, const unsigned short* __restrict__ Wtr,
    float* __restrict__ wc)
{
    __shared__ short As[128][72];
    __shared__ short Bs[128][72];
    const int m0 = blockIdx.x * 128;
    const int n0 = blockIdx.y * 128;
    const int t = threadIdx.x;
    const int r = t >> 1;
    const int half = t & 1;
    const float*          arow = c + (size_t)(m0 + r) * Hq + half * 32;
    const unsigned short* brow = Wtr + (size_t)(n0 + r) * Hq + half * 32;
    const int lane = t & 63;
    const int w = t >> 6;
    const int wm = (w & 1) * 64;
    const int wn = (w >> 1) * 64;
    const int l15 = lane & 15;
    const int q = lane >> 4;
    floatx4 acc[4][4] = {};
    for (int k0 = 0; k0 < Hq; k0 += 64) {
        __syncthreads();
        const float4* a4 = reinterpret_cast<const float4*>(arow + k0);
        #pragma unroll
        for (int i = 0; i < 4; ++i) {
            float4 v0 = a4[2 * i], v1 = a4[2 * i + 1];
            short8 p;
            p[0] = f2b(v0.x); p[1] = f2b(v0.y); p[2] = f2b(v0.z); p[3] = f2b(v0.w);
            p[4] = f2b(v1.x); p[5] = f2b(v1.y); p[6] = f2b(v1.z); p[7] = f2b(v1.w);
            *reinterpret_cast<short8*>(&As[r][half * 32 + i * 8]) = p;
        }
        const short8* b8 = reinterpret_cast<const short8*>(brow + k0);
        #pragma unroll
        for (int i = 0; i < 4; ++i)
            *reinterpret_cast<short8*>(&Bs[r][half * 32 + i * 8]) = b8[i];
        __syncthreads();
        #pragma unroll
        for (int kk = 0; kk < 64; kk += 32) {
            short8 af[4], bfr[4];
            #pragma unroll
            for (int i = 0; i < 4; ++i)
                af[i] = *reinterpret_cast<const short8*>(&As[wm + i * 16 + l15][kk + q * 8]);
            #pragma unroll
            for (int j = 0; j < 4; ++j)
                bfr[j] = *reinterpret_cast<const short8*>(&Bs[wn + j * 16 + l15][kk + q * 8]);
            #pragma unroll
            for (int i = 0; i < 4; ++i)
                #pragma unroll
                for (int j = 0; j < 4; ++j)
                    acc[i][j] = __builtin_amdgcn_mfma_f32_16x16x32_bf16(
                        af[i], bfr[j], acc[i][j], 0, 0, 0);
        }
    }
    #pragma unroll
    for (int i = 0; i < 4; ++i)
        #pragma unroll
        for (int rr = 0; rr < 4; ++rr) {
            const int mm = m0 + wm + i * 16 + q * 4 + rr;
            #pragma unroll
            for (int j = 0; j < 4; ++j)
                wc[(size_t)mm * Hq + n0 + wn + j * 16 + l15] = acc[i][j][rr];
        }
}

__global__ __launch_bounds__(256, 2) void gemm_scores_fb(
    const float* __restrict__ allh, const unsigned short* __restrict__ Vt,
    const float* __restrict__ wc, const float* __restrict__ bias,
    const float* __restrict__ Wt, float* __restrict__ scores)
{
    __shared__ short As[128][72];
    __shared__ short Bs[128][72];
    const int m0 = blockIdx.x * 128;
    const int n0 = blockIdx.y * 128;
    const int t = threadIdx.x;
    const int r = t >> 1;
    const int half = t & 1;
    const int m = m0 + r;
    const int bb = m / 21;
    const int ss = m - bb * 21;
    const float* arow = allh + (size_t)ss * (Bq * Hq) + (size_t)bb * Hq + half * 32;
    const unsigned short* brow = Vt + (size_t)(n0 + r) * Hq + half * 32;
    const int lane = t & 63;
    const int w = t >> 6;
    const int wm = (w & 1) * 64;
    const int wn = (w >> 1) * 64;
    const int l15 = lane & 15;
    const int q = lane >> 4;
    floatx4 acc[4][4] = {};
    for (int k0 = 0; k0 < Hq; k0 += 64) {
        __syncthreads();
        const float4* a4 = reinterpret_cast<const float4*>(arow + k0);
        #pragma unroll
        for (int i = 0; i < 4; ++i) {
            float4 v0 = a4[2 * i], v1 = a4[2 * i + 1];
            short8 p;
            p[0] = f2b(v0.x); p[1] = f2b(v0.y); p[2] = f2b(v0.z); p[3] = f2b(v0.w);
            p[4] = f2b(v1.x); p[5] = f2b(v1.y); p[6] = f2b(v1.z); p[7] = f2b(v1.w);
            *reinterpret_cast<short8*>(&As[r][half * 32 + i * 8]) = p;
        }
        const short8* b8 = reinterpret_cast<const short8*>(brow + k0);
        #pragma unroll
        for (int i = 0; i < 4; ++i)
            *reinterpret_cast<short8*>(&Bs[r][half * 32 + i * 8]) = b8[i];
        __syncthreads();
        #pragma unroll
        for (int kk = 0; kk < 64; kk += 32) {
            short8 af[4], bfr[4];
            #pragma unroll
            for (int i = 0; i < 4; ++i)
                af[i] = *reinterpret_cast<const short8*>(&As[wm + i * 16 + l15][kk + q * 8]);
            #pragma unroll
            for (int j = 0; j < 4; ++j)
                bfr[j] = *reinterpret_cast<const short8*>(&Bs[wn + j * 16 + l15][kk + q * 8]);
            #pragma unroll
            for (int i = 0; i < 4; ++i)
                #pragma unroll
                for (int j = 0; j < 4; ++j)
                    acc[i][j] = __builtin_amdgcn_mfma_f32_16x16x32_bf16(
                        af[i], bfr[j], acc[i][j], 0, 0, 0);
        }
    }
    float wtv[4];
    #pragma unroll
    for (int j = 0; j < 4; ++j) wtv[j] = Wt[n0 + wn + j * 16 + l15];
    #pragma unroll
    for (int i = 0; i < 4; ++i)
        #pragma unroll
        for (int rr = 0; rr < 4; ++rr) {
            const int mm = m0 + wm + i * 16 + q * 4 + rr;
            const int b2 = mm / 21;
            const int s2 = mm - b2 * 21;
            const float* wcrow = wc + (size_t)b2 * Hq + n0 + wn;
            const float* birow = bias + (size_t)s2 * Hq + n0 + wn;
            float part = 0.f;
            #pragma unroll
            for (int j = 0; j < 4; ++j) {
                const int nl = j * 16 + l15;
                float e = tanhf(acc[i][j][rr] + wcrow[nl] + birow[nl]);
                part += e * wtv[j];
            }
            part += __shfl_xor(part, 1);
            part += __shfl_xor(part, 2);
            part += __shfl_xor(part, 4);
            part += __shfl_xor(part, 8);
            if (l15 == 0) atomicAdd(&scores[mm], part);
        }
}

__global__ __launch_bounds__(256) void softmax_out_fb(
    const float* __restrict__ scores, const float* __restrict__ allh,
    float* __restrict__ out)
{
    const int b = blockIdx.x;
    const int t = threadIdx.x;
    float sc[Sq];
    float mx = -1e30f;
    #pragma unroll
    for (int s = 0; s < Sq; ++s) {
        sc[s] = scores[(size_t)b * Sq + s];
        mx = fmaxf(mx, sc[s]);
    }
    float sum = 0.f;
    #pragma unroll
    for (int s = 0; s < Sq; ++s) {
        sc[s] = __expf(sc[s] - mx);
        sum += sc[s];
    }
    const float inv = 1.0f / sum;
    for (int h = t; h < Hq; h += 256) {
        float acc = 0.f;
        #pragma unroll
        for (int s = 0; s < Sq; ++s)
            acc += sc[s] * allh[(size_t)s * (Bq * Hq) + (size_t)b * Hq + h];
        out[(size_t)b * Hq + h] = acc * inv;
    }
}

// ---------------------------------------------------------------------------
extern "C" void kernel_launch(void* const* d_in, const int* in_sizes, int n_in,
                              void* d_out, int out_size, void* d_ws, size_t ws_size,
                              hipStream_t stream) {
    const float* c    = (const float*)d_in[0];
    const float* allh = (const float*)d_in[1];
    const float* W    = (const float*)d_in[2];
    const float* V    = (const float*)d_in[3];
    const float* bias = (const float*)d_in[4];
    const float* Wt   = (const float*)d_in[5];
    float* out = (float*)d_out;
    char* ws = (char*)d_ws;

    const size_t NEED = 411041792ULL;  // ~392 MiB fast-path scratch

    if (ws_size >= NEED) {
        unsigned short* Vt  = (unsigned short*)ws;                 // 2 MB
        unsigned short* Wtr = (unsigned short*)(ws + 2097152);     // 2 MB
        float* wc           = (float*)(ws + 4194304);              // 32 MB
        float* scores       = (float*)(ws + 37748736);             // 688 KB
        unsigned short* cb  = (unsigned short*)(ws + 41943040);    // 16 MB
        unsigned short* hb  = (unsigned short*)(ws + 58720256);    // 336 MB

        hipMemsetAsync(scores, 0, (size_t)Bq * Sq * sizeof(float), stream);
        transpose_cvt<<<dim3(32, 32), dim3(32, 8), 0, stream>>>(W, Wtr);
        transpose_cvt<<<dim3(32, 32), dim3(32, 8), 0, stream>>>(V, Vt);
        cvt_bf16<<<1024, 256, 0, stream>>>(c, cb, Bq * Hq / 8);
        cvt_bf16<<<4096, 256, 0, stream>>>(allh, hb, Sq * (Bq / 8) * Hq);

        gemm_wc2<<<dim3(Hq / 128, Bq / 128), 256, 0, stream>>>(cb, Wtr, wc);
        gemm_scores_p3<<<dim3((Mq / 128) * (Hq / 256)), dim3(512), 0, stream>>>(
            hb, Vt, wc, bias, Wt, scores);
        softmax_out2<<<Bq, 256, 0, stream>>>(scores, hb, out);
    } else {
        unsigned short* Vt  = (unsigned short*)ws;
        unsigned short* Wtr = (unsigned short*)(ws + (2u << 20));
        float* wc     = (float*)(ws + (4u << 20));
        float* scores = (float*)(ws + (4u << 20) + (size_t)Bq * Hq * 4);

        hipMemsetAsync(scores, 0, (size_t)Bq * Sq * sizeof(float), stream);
        transpose_cvt<<<dim3(32, 32), dim3(32, 8), 0, stream>>>(W, Wtr);
        transpose_cvt<<<dim3(32, 32), dim3(32, 8), 0, stream>>>(V, Vt);
        gemm_wc_fb<<<dim3(Bq / 128, Hq / 128), 256, 0, stream>>>(c, Wtr, wc);
        gemm_scores_fb<<<dim3(Mq / 128, Hq / 128), 256, 0, stream>>>(
            allh, Vt, wc, bias, Wt, scores);
        softmax_out_fb<<<Bq, 256, 0, stream>>>(scores, allh, out);
    }
}